// Round 2
// baseline (2218.591 us; speedup 1.0000x reference)
//
#include <hip/hip_runtime.h>
#include <math.h>

// B=4, N=4096, M=16384, Eg=65536, Ea=65536, D=512, DK=64
#define BB 4
#define NT 4096
#define ME 16384
#define EG 65536
#define EA 65536
#define DD 512
#define DKK 64

// ---------------- per-sample kernels ----------------

__global__ void k_deg(const int* __restrict__ dst, float* __restrict__ deg) {
    int e = blockIdx.x * blockDim.x + threadIdx.x;
    if (e < EG) atomicAdd(&deg[dst[e]], 1.0f);
}

__global__ void k_dinv(float* __restrict__ deg) {
    int i = blockIdx.x * blockDim.x + threadIdx.x;
    if (i < ME) deg[i] = rsqrtf(deg[i] + 1.0f);  // +1 self loop; deg>=0
}

// z[m,:] = dinv[m] * t[t2e[m],:]
__global__ void k_zinit(const float* __restrict__ t, const int* __restrict__ t2e,
                        const float* __restrict__ dinv, float* __restrict__ z) {
    int i = blockIdx.x * blockDim.x + threadIdx.x;  // ME*DD/4 threads
    int m = i >> 7;                                  // DD/4 = 128
    int d4 = (i & 127) << 2;
    float4 v = *(const float4*)(t + ((long)t2e[m] << 9) + d4);
    float s = dinv[m];
    v.x *= s; v.y *= s; v.z *= s; v.w *= s;
    *(float4*)(z + ((long)m << 9) + d4) = v;
}

// z[dst,:] += dinv[src] * t[t2e[src],:]
__global__ void k_zscatter(const float* __restrict__ t, const int* __restrict__ t2e,
                           const float* __restrict__ dinv, const int* __restrict__ ei,
                           float* __restrict__ z) {
    long i = (long)blockIdx.x * blockDim.x + threadIdx.x;  // EG*DD
    int d = (int)(i & (DD - 1));
    int e = (int)(i >> 9);
    int s = ei[e];
    int dst = ei[EG + e];
    float val = dinv[s] * t[((long)t2e[s] << 9) + d];
    atomicAdd(&z[((long)dst << 9) + d], val);
}

// ---------------- fp32 tiled GEMM: C[Mr,Nc] = rowscale(A)[Mr,K] @ Bw[K,Nc] + bias ----------------
// BM=BN=64, BK=16, 256 threads, 4x4 micro-tile. All dims divide evenly here.
template<bool ROWSCALE, bool BIAS>
__global__ void gemm_tiled(const float* __restrict__ A, const float* __restrict__ rowscale,
                           const float* __restrict__ Bw, const float* __restrict__ bias,
                           float* __restrict__ C, int K, int Nc) {
    __shared__ float As[16][64];
    __shared__ float Bs[16][64];
    int tid = threadIdx.x;
    int tx = tid & 15, ty = tid >> 4;
    int bm = blockIdx.x * 64, bn = blockIdx.y * 64;
    float acc[4][4] = {};
    int arow = bm + (tid >> 2);
    long aoff = (long)arow * K;
    float rs = ROWSCALE ? rowscale[arow] : 1.0f;
    int kk0 = (tid & 3) * 4;
    int arowl = tid >> 2;
    for (int k0 = 0; k0 < K; k0 += 16) {
        float4 av = *(const float4*)(A + aoff + k0 + kk0);
        if (ROWSCALE) { av.x *= rs; av.y *= rs; av.z *= rs; av.w *= rs; }
        As[kk0 + 0][arowl] = av.x;
        As[kk0 + 1][arowl] = av.y;
        As[kk0 + 2][arowl] = av.z;
        As[kk0 + 3][arowl] = av.w;
        float4 bv = *(const float4*)(Bw + (long)(k0 + (tid >> 4)) * Nc + bn + (tid & 15) * 4);
        *(float4*)&Bs[tid >> 4][(tid & 15) * 4] = bv;
        __syncthreads();
#pragma unroll
        for (int k = 0; k < 16; ++k) {
            float4 a = *(const float4*)&As[k][ty * 4];
            float4 b = *(const float4*)&Bs[k][tx * 4];
            acc[0][0] += a.x * b.x; acc[0][1] += a.x * b.y; acc[0][2] += a.x * b.z; acc[0][3] += a.x * b.w;
            acc[1][0] += a.y * b.x; acc[1][1] += a.y * b.y; acc[1][2] += a.y * b.z; acc[1][3] += a.y * b.w;
            acc[2][0] += a.z * b.x; acc[2][1] += a.z * b.y; acc[2][2] += a.z * b.z; acc[2][3] += a.z * b.w;
            acc[3][0] += a.w * b.x; acc[3][1] += a.w * b.y; acc[3][2] += a.w * b.z; acc[3][3] += a.w * b.w;
        }
        __syncthreads();
    }
#pragma unroll
    for (int i = 0; i < 4; ++i) {
        float4 v = make_float4(acc[i][0], acc[i][1], acc[i][2], acc[i][3]);
        if (BIAS) {
            const float4 bb = *(const float4*)(bias + bn + tx * 4);
            v.x += bb.x; v.y += bb.y; v.z += bb.z; v.w += bb.w;
        }
        *(float4*)(C + (long)(bm + ty * 4 + i) * Nc + bn + tx * 4) = v;
    }
}

// ---------------- attention dots: one wave per edge (biases already folded into k/q) ----------------
__global__ void k_dots(const float* __restrict__ kmat, const float* __restrict__ qmat,
                       const int* __restrict__ esrc, const int* __restrict__ edst,
                       float* __restrict__ wbuf, float* __restrict__ den) {
    long gid = (long)blockIdx.x * blockDim.x + threadIdx.x;
    int lane = (int)(gid & 63);
    long e = gid >> 6;
    if (e >= EA) return;
    int s = esrc[e], dd = edst[e];
    float p = qmat[((long)dd << 6) + lane] * kmat[((long)s << 6) + lane];
#pragma unroll
    for (int off = 32; off > 0; off >>= 1) p += __shfl_down(p, off);
    if (lane == 0) {
        float w = expf(p * 0.125f);  // /sqrt(64); max-shift is exact no-op (shift invariance)
        wbuf[e] = w;
        atomicAdd(&den[dd], w);
    }
}

// ---------------- gatt[dst,:] += w[e] * ee[src,:] ----------------
__global__ void k_att_scatter(const float* __restrict__ ee, const float* __restrict__ wbuf,
                              const int* __restrict__ esrc, const int* __restrict__ edst,
                              float* __restrict__ gatt) {
    long i = (long)blockIdx.x * blockDim.x + threadIdx.x;  // EA*DD
    int d = (int)(i & (DD - 1));
    int e = (int)(i >> 9);
    int s = esrc[e], dd = edst[e];
    float val = wbuf[e] * ee[((long)s << 9) + d];
    atomicAdd(&gatt[((long)dd << 9) + d], val);
}

// ---------------- newt = t + tanh(ga) * gatt/den  (into d_out) ----------------
__global__ void k_new(const float* __restrict__ t, const float* __restrict__ gatt,
                      const float* __restrict__ den, const float* __restrict__ ga,
                      float* __restrict__ outb) {
    long i = (long)blockIdx.x * blockDim.x + threadIdx.x;  // NT*DD
    long row = i >> 9;
    float dn = den[row];
    float g = tanhf(ga[0]);
    float val = dn > 0.0f ? gatt[i] / dn : 0.0f;
    outb[i] = t[i] + g * val;
}

// ---------------- out += tanh(gb) * lin  (lin already has +bl) ----------------
__global__ void k_final(float* __restrict__ outb, const float* __restrict__ lin,
                        const float* __restrict__ gb) {
    long i = (long)blockIdx.x * blockDim.x + threadIdx.x;  // NT*DD
    float g = tanhf(gb[0]);
    outb[i] = outb[i] + g * lin[i];
}

extern "C" void kernel_launch(void* const* d_in, const int* in_sizes, int n_in,
                              void* d_out, int out_size, void* d_ws, size_t ws_size,
                              hipStream_t stream) {
    const float* t_all   = (const float*)d_in[0];   // [B,N,D]
    const int*   t2e_all = (const int*)d_in[1];     // [B,M]
    const int*   ei_all  = (const int*)d_in[2];     // [B,2,Eg]
    const int*   es_all  = (const int*)d_in[3];     // [B,Ea]
    const int*   ed_all  = (const int*)d_in[4];     // [B,Ea]
    const float* Wgnn    = (const float*)d_in[5];
    const float* bgnn    = (const float*)d_in[6];
    const float* Wk      = (const float*)d_in[7];
    const float* bk      = (const float*)d_in[8];
    const float* Wq      = (const float*)d_in[9];
    const float* bq      = (const float*)d_in[10];
    const float* Wl      = (const float*)d_in[11];
    const float* bl      = (const float*)d_in[12];
    const float* ga      = (const float*)d_in[13];
    const float* gb      = (const float*)d_in[14];
    float* out = (float*)d_out;

    // per-sample workspace, reused across the 4 samples (~77 MB total)
    float* ws = (float*)d_ws;
    size_t off = 0;
    float* z    = ws + off; off += (size_t)ME * DD;   // 33.5 MB
    float* ee   = ws + off; off += (size_t)ME * DD;   // 33.5 MB
    float* gl   = ws + off; off += (size_t)NT * DD;   // 8.4 MB (gatt, then lin)
    float* kmat = ws + off; off += (size_t)ME * DKK;  // 4.2 MB
    float* qmat = ws + off; off += (size_t)NT * DKK;  // 1.0 MB
    float* dinv = ws + off; off += (size_t)ME;
    float* den  = ws + off; off += (size_t)NT;
    float* wbuf = ws + off; off += (size_t)EA;

    for (int b = 0; b < BB; ++b) {
        const float* t   = t_all + (size_t)b * NT * DD;
        const int*   t2e = t2e_all + (size_t)b * ME;
        const int*   ei  = ei_all + (size_t)b * 2 * EG;
        const int*   es  = es_all + (size_t)b * EA;
        const int*   ed  = ed_all + (size_t)b * EA;
        float* outb = out + (size_t)b * NT * DD;

        hipMemsetAsync(dinv, 0, (size_t)ME * sizeof(float), stream);
        hipMemsetAsync(den, 0, (size_t)NT * sizeof(float), stream);
        hipMemsetAsync(gl, 0, (size_t)NT * DD * sizeof(float), stream);

        k_deg<<<EG / 256, 256, 0, stream>>>(ei + EG, dinv);
        k_dinv<<<ME / 256, 256, 0, stream>>>(dinv);

        k_zinit<<<(ME * DD / 4) / 256, 256, 0, stream>>>(t, t2e, dinv, z);
        k_zscatter<<<(int)(((long)EG * DD) / 256), 256, 0, stream>>>(t, t2e, dinv, ei, z);

        // ee = (dinv ⊙ z) @ Wgnn + bgnn       [M,512]
        gemm_tiled<true, true><<<dim3(ME / 64, DD / 64), 256, 0, stream>>>(
            z, dinv, Wgnn, bgnn, ee, DD, DD);

        // kmat = ee @ Wk + bk  [M,64] ; qmat = t @ Wq + bq  [N,64]
        gemm_tiled<false, true><<<dim3(ME / 64, 1), 256, 0, stream>>>(
            ee, nullptr, Wk, bk, kmat, DD, DKK);
        gemm_tiled<false, true><<<dim3(NT / 64, 1), 256, 0, stream>>>(
            t, nullptr, Wq, bq, qmat, DD, DKK);

        k_dots<<<(int)(((long)EA * 64) / 256), 256, 0, stream>>>(kmat, qmat, es, ed, wbuf, den);
        k_att_scatter<<<(int)(((long)EA * DD) / 256), 256, 0, stream>>>(ee, wbuf, es, ed, gl);

        k_new<<<(int)(((long)NT * DD) / 256), 256, 0, stream>>>(t, gl, den, ga, outb);

        // lin = newt @ Wl + bl  [N,512]  (gl reused — gatt dead after k_new)
        gemm_tiled<false, true><<<dim3(NT / 64, DD / 64), 256, 0, stream>>>(
            outb, nullptr, Wl, bl, gl, DD, DD);

        k_final<<<(int)(((long)NT * DD) / 256), 256, 0, stream>>>(outb, gl, gb);
    }
}

// Round 3
// 1706.646 us; speedup vs baseline: 1.3000x; 1.3000x over previous
//
#include <hip/hip_runtime.h>
#include <math.h>

// B=4, N=4096, M=16384, Eg=65536, Ea=65536, D=512, DK=64
#define BB 4
#define NT 4096
#define ME 16384
#define EG 65536
#define EA 65536
#define DD 512
#define DKK 64

using bf16x8 = __attribute__((ext_vector_type(8))) short;
using f32x4  = __attribute__((ext_vector_type(4))) float;

// round-to-nearest-even f32 -> bf16 (finite inputs only)
static __device__ __forceinline__ unsigned short f2bf(float f) {
    unsigned u = __float_as_uint(f);
    u += 0x7fffu + ((u >> 16) & 1u);
    return (unsigned short)(u >> 16);
}

// ---------------- per-sample prep ----------------

__global__ void k_deg(const int* __restrict__ dst, float* __restrict__ deg) {
    int e = blockIdx.x * blockDim.x + threadIdx.x;
    if (e < EG) atomicAdd(&deg[dst[e]], 1.0f);
}

__global__ void k_dinv(float* __restrict__ deg) {
    int i = blockIdx.x * blockDim.x + threadIdx.x;
    if (i < ME) deg[i] = rsqrtf(deg[i] + 1.0f);  // +1 self loop
}

// z[m,:] = dinv[m] * t[t2e[m],:]
__global__ void k_zinit(const float* __restrict__ t, const int* __restrict__ t2e,
                        const float* __restrict__ dinv, float* __restrict__ z) {
    int i = blockIdx.x * blockDim.x + threadIdx.x;  // ME*DD/4
    int m = i >> 7;
    int d4 = (i & 127) << 2;
    float4 v = *(const float4*)(t + ((long)t2e[m] << 9) + d4);
    float s = dinv[m];
    v.x *= s; v.y *= s; v.z *= s; v.w *= s;
    *(float4*)(z + ((long)m << 9) + d4) = v;
}

// z[dst,:] += dinv[src] * t[t2e[src],:]
__global__ void k_zscatter(const float* __restrict__ t, const int* __restrict__ t2e,
                           const float* __restrict__ dinv, const int* __restrict__ ei,
                           float* __restrict__ z) {
    long i = (long)blockIdx.x * blockDim.x + threadIdx.x;  // EG*DD
    int d = (int)(i & (DD - 1));
    int e = (int)(i >> 9);
    int s = ei[e];
    int dst = ei[EG + e];
    float val = dinv[s] * t[((long)t2e[s] << 9) + d];
    atomicAdd(&z[((long)dst << 9) + d], val);
}

// zb = bf16(dinv[m] * z)   (rowscale for the GCN D^{-1/2} on the dst side)
__global__ void k_cast_rs(const float* __restrict__ z, const float* __restrict__ dinv,
                          unsigned short* __restrict__ zb) {
    long i = (long)blockIdx.x * blockDim.x + threadIdx.x;  // ME*DD/4
    int m = (int)(i >> 7);
    float s = dinv[m];
    float4 v = *(const float4*)(z + (i << 2));
    ushort4 o;
    o.x = f2bf(v.x * s); o.y = f2bf(v.y * s); o.z = f2bf(v.z * s); o.w = f2bf(v.w * s);
    *(ushort4*)(zb + (i << 2)) = o;
}

// plain fp32 -> bf16 cast
__global__ void k_cast(const float* __restrict__ x, unsigned short* __restrict__ xb) {
    long i = (long)blockIdx.x * blockDim.x + threadIdx.x;  // count/4
    float4 v = *(const float4*)(x + (i << 2));
    ushort4 o;
    o.x = f2bf(v.x); o.y = f2bf(v.y); o.z = f2bf(v.z); o.w = f2bf(v.w);
    *(ushort4*)(xb + (i << 2)) = o;
}

// Wt[n][k] = bf16(W[k][n])   (512x512)
__global__ void k_wt(const float* __restrict__ W, unsigned short* __restrict__ Wt) {
    int i = blockIdx.x * blockDim.x + threadIdx.x;  // 512*512
    int n = i >> 9, k = i & 511;
    Wt[i] = f2bf(W[((long)k << 9) + n]);
}

// ---------------- bf16 MFMA GEMM (m97 structure): C[M,N] = A[M,K] @ Bt[N,K]^T + bias ----------------
// 128x128 tile, BK=32, 256 threads = 4 waves in 2x2; wave does 4x4 grid of 16x16x32 MFMAs.
__global__ __launch_bounds__(256) void gemm_bt_mfma(
    const unsigned short* __restrict__ A,   // [M,K] bf16 row-major
    const unsigned short* __restrict__ Bt,  // [N,K] bf16 (weights pre-transposed)
    const float* __restrict__ bias,         // [N]
    float* __restrict__ C, int M, int N, int K)
{
    __shared__ short As[128 * 32];
    __shared__ short Bs[128 * 32];
    int tid = threadIdx.x;
    int lane = tid & 63;
    int w = tid >> 6;
    int wm = w >> 1, wn = w & 1;
    int bm = blockIdx.x * 128, bn = blockIdx.y * 128;

    f32x4 acc[4][4] = {};

    // staging map: per 4KB chunk, thread tid -> lds byte tid*16, global row = chunk*64 + tid/4,
    // k-offset = (tid&3)*8 elems. LDS dest is wave-uniform base + lane*16 (global_load_lds rule).
    int srow = tid >> 2;
    int scol = (tid & 3) * 8;
    const unsigned short* Ag0 = A + (long)(bm + srow) * K + scol;
    const unsigned short* Ag1 = A + (long)(bm + 64 + srow) * K + scol;
    const unsigned short* Bg0 = Bt + (long)(bn + srow) * K + scol;
    const unsigned short* Bg1 = Bt + (long)(bn + 64 + srow) * K + scol;

    int ar = wm * 64 + (lane & 15);   // A-tile row for rb-block (+rb*16)
    int br = wn * 64 + (lane & 15);   // Bt-tile row for cb-block (+cb*16)
    int kq = (lane >> 4) * 8;         // k quad offset

    for (int k0 = 0; k0 < K; k0 += 32) {
        __builtin_amdgcn_global_load_lds(
            (const __attribute__((address_space(1))) unsigned int*)(Ag0 + k0),
            (__attribute__((address_space(3))) unsigned int*)(As + tid * 8), 16, 0, 0);
        __builtin_amdgcn_global_load_lds(
            (const __attribute__((address_space(1))) unsigned int*)(Ag1 + k0),
            (__attribute__((address_space(3))) unsigned int*)(As + 2048 + tid * 8), 16, 0, 0);
        __builtin_amdgcn_global_load_lds(
            (const __attribute__((address_space(1))) unsigned int*)(Bg0 + k0),
            (__attribute__((address_space(3))) unsigned int*)(Bs + tid * 8), 16, 0, 0);
        __builtin_amdgcn_global_load_lds(
            (const __attribute__((address_space(1))) unsigned int*)(Bg1 + k0),
            (__attribute__((address_space(3))) unsigned int*)(Bs + 2048 + tid * 8), 16, 0, 0);
        __syncthreads();  // compiler emits vmcnt(0) drain before s_barrier

        bf16x8 af[4], bf[4];
#pragma unroll
        for (int rb = 0; rb < 4; ++rb)
            af[rb] = *(const bf16x8*)&As[(ar + rb * 16) * 32 + kq];
#pragma unroll
        for (int cb = 0; cb < 4; ++cb)
            bf[cb] = *(const bf16x8*)&Bs[(br + cb * 16) * 32 + kq];
#pragma unroll
        for (int rb = 0; rb < 4; ++rb)
#pragma unroll
            for (int cb = 0; cb < 4; ++cb)
                acc[rb][cb] = __builtin_amdgcn_mfma_f32_16x16x32_bf16(
                    af[rb], bf[cb], acc[rb][cb], 0, 0, 0);
        __syncthreads();
    }

    // C/D layout: col = lane&15, row = (lane>>4)*4 + reg
#pragma unroll
    for (int rb = 0; rb < 4; ++rb) {
        int row0 = bm + wm * 64 + rb * 16 + ((lane >> 4) << 2);
#pragma unroll
        for (int cb = 0; cb < 4; ++cb) {
            int col = bn + wn * 64 + cb * 16 + (lane & 15);
            float bv = bias[col];
            float* cp = C + (long)row0 * N + col;
#pragma unroll
            for (int r = 0; r < 4; ++r)
                cp[(long)r * N] = acc[rb][cb][r] + bv;
        }
    }
}

// ---------------- fp32 tiled GEMM (kept for skinny k/q projections) ----------------
template<bool ROWSCALE, bool BIAS>
__global__ void gemm_tiled(const float* __restrict__ A, const float* __restrict__ rowscale,
                           const float* __restrict__ Bw, const float* __restrict__ bias,
                           float* __restrict__ C, int K, int Nc) {
    __shared__ float As[16][64];
    __shared__ float Bs[16][64];
    int tid = threadIdx.x;
    int tx = tid & 15, ty = tid >> 4;
    int bm = blockIdx.x * 64, bn = blockIdx.y * 64;
    float acc[4][4] = {};
    int arow = bm + (tid >> 2);
    long aoff = (long)arow * K;
    float rs = ROWSCALE ? rowscale[arow] : 1.0f;
    int kk0 = (tid & 3) * 4;
    int arowl = tid >> 2;
    for (int k0 = 0; k0 < K; k0 += 16) {
        float4 av = *(const float4*)(A + aoff + k0 + kk0);
        if (ROWSCALE) { av.x *= rs; av.y *= rs; av.z *= rs; av.w *= rs; }
        As[kk0 + 0][arowl] = av.x;
        As[kk0 + 1][arowl] = av.y;
        As[kk0 + 2][arowl] = av.z;
        As[kk0 + 3][arowl] = av.w;
        float4 bv = *(const float4*)(Bw + (long)(k0 + (tid >> 4)) * Nc + bn + (tid & 15) * 4);
        *(float4*)&Bs[tid >> 4][(tid & 15) * 4] = bv;
        __syncthreads();
#pragma unroll
        for (int k = 0; k < 16; ++k) {
            float4 a = *(const float4*)&As[k][ty * 4];
            float4 b = *(const float4*)&Bs[k][tx * 4];
            acc[0][0] += a.x * b.x; acc[0][1] += a.x * b.y; acc[0][2] += a.x * b.z; acc[0][3] += a.x * b.w;
            acc[1][0] += a.y * b.x; acc[1][1] += a.y * b.y; acc[1][2] += a.y * b.z; acc[1][3] += a.y * b.w;
            acc[2][0] += a.z * b.x; acc[2][1] += a.z * b.y; acc[2][2] += a.z * b.z; acc[2][3] += a.z * b.w;
            acc[3][0] += a.w * b.x; acc[3][1] += a.w * b.y; acc[3][2] += a.w * b.z; acc[3][3] += a.w * b.w;
        }
        __syncthreads();
    }
#pragma unroll
    for (int i = 0; i < 4; ++i) {
        float4 v = make_float4(acc[i][0], acc[i][1], acc[i][2], acc[i][3]);
        if (BIAS) {
            const float4 bb = *(const float4*)(bias + bn + tx * 4);
            v.x += bb.x; v.y += bb.y; v.z += bb.z; v.w += bb.w;
        }
        *(float4*)(C + (long)(bm + ty * 4 + i) * Nc + bn + tx * 4) = v;
    }
}

// ---------------- attention ----------------
__global__ void k_dots(const float* __restrict__ kmat, const float* __restrict__ qmat,
                       const int* __restrict__ esrc, const int* __restrict__ edst,
                       float* __restrict__ wbuf, float* __restrict__ den) {
    long gid = (long)blockIdx.x * blockDim.x + threadIdx.x;
    int lane = (int)(gid & 63);
    long e = gid >> 6;
    if (e >= EA) return;
    int s = esrc[e], dd = edst[e];
    float p = qmat[((long)dd << 6) + lane] * kmat[((long)s << 6) + lane];
#pragma unroll
    for (int off = 32; off > 0; off >>= 1) p += __shfl_down(p, off);
    if (lane == 0) {
        float w = expf(p * 0.125f);  // softmax max-shift is an exact no-op (shift invariance)
        wbuf[e] = w;
        atomicAdd(&den[dd], w);
    }
}

__global__ void k_att_scatter(const float* __restrict__ ee, const float* __restrict__ wbuf,
                              const int* __restrict__ esrc, const int* __restrict__ edst,
                              float* __restrict__ gatt) {
    long i = (long)blockIdx.x * blockDim.x + threadIdx.x;  // EA*DD
    int d = (int)(i & (DD - 1));
    int e = (int)(i >> 9);
    int s = esrc[e], dd = edst[e];
    float val = wbuf[e] * ee[((long)s << 9) + d];
    atomicAdd(&gatt[((long)dd << 9) + d], val);
}

// newt = t + tanh(ga) * gatt/den  (into d_out)
__global__ void k_new(const float* __restrict__ t, const float* __restrict__ gatt,
                      const float* __restrict__ den, const float* __restrict__ ga,
                      float* __restrict__ outb) {
    long i = (long)blockIdx.x * blockDim.x + threadIdx.x;  // NT*DD
    long row = i >> 9;
    float dn = den[row];
    float g = tanhf(ga[0]);
    float val = dn > 0.0f ? gatt[i] / dn : 0.0f;
    outb[i] = t[i] + g * val;
}

// out += tanh(gb) * lin   (lin already has +bl)
__global__ void k_final(float* __restrict__ outb, const float* __restrict__ lin,
                        const float* __restrict__ gb) {
    long i = (long)blockIdx.x * blockDim.x + threadIdx.x;
    float g = tanhf(gb[0]);
    outb[i] = outb[i] + g * lin[i];
}

extern "C" void kernel_launch(void* const* d_in, const int* in_sizes, int n_in,
                              void* d_out, int out_size, void* d_ws, size_t ws_size,
                              hipStream_t stream) {
    const float* t_all   = (const float*)d_in[0];
    const int*   t2e_all = (const int*)d_in[1];
    const int*   ei_all  = (const int*)d_in[2];
    const int*   es_all  = (const int*)d_in[3];
    const int*   ed_all  = (const int*)d_in[4];
    const float* Wgnn    = (const float*)d_in[5];
    const float* bgnn    = (const float*)d_in[6];
    const float* Wk      = (const float*)d_in[7];
    const float* bk      = (const float*)d_in[8];
    const float* Wq      = (const float*)d_in[9];
    const float* bq      = (const float*)d_in[10];
    const float* Wl      = (const float*)d_in[11];
    const float* bl      = (const float*)d_in[12];
    const float* ga      = (const float*)d_in[13];
    const float* gb      = (const float*)d_in[14];
    float* out = (float*)d_out;

    // workspace (~91 MB peak, reused across samples)
    char* wsb = (char*)d_ws;
    size_t off = 0;
    float* z    = (float*)(wsb + off); off += (size_t)ME * DD * 4;      // 33.5 MB
    float* ee   = (float*)(wsb + off); off += (size_t)ME * DD * 4;      // 33.5 MB
    // region X (16.78 MB): phase-1 = zb (ME*DD bf16); phase-2 = gl (NT*DD f32) + nb (NT*DD bf16)
    char* X = wsb + off; off += (size_t)ME * DD * 2;
    unsigned short* zb = (unsigned short*)X;
    float*          gl = (float*)X;
    unsigned short* nb = (unsigned short*)(X + (size_t)NT * DD * 4);
    float* kmat = (float*)(wsb + off); off += (size_t)ME * DKK * 4;     // 4.2 MB
    float* qmat = (float*)(wsb + off); off += (size_t)NT * DKK * 4;     // 1.0 MB
    unsigned short* Wgt = (unsigned short*)(wsb + off); off += (size_t)DD * DD * 2;
    unsigned short* Wlt = (unsigned short*)(wsb + off); off += (size_t)DD * DD * 2;
    float* dinv = (float*)(wsb + off); off += (size_t)ME * 4;
    float* den  = (float*)(wsb + off); off += (size_t)NT * 4;
    float* wbuf = (float*)(wsb + off); off += (size_t)EA * 4;

    // one-time weight transpose-casts
    k_wt<<<(DD * DD) / 256, 256, 0, stream>>>(Wgnn, Wgt);
    k_wt<<<(DD * DD) / 256, 256, 0, stream>>>(Wl, Wlt);

    for (int b = 0; b < BB; ++b) {
        const float* t   = t_all + (size_t)b * NT * DD;
        const int*   t2e = t2e_all + (size_t)b * ME;
        const int*   ei  = ei_all + (size_t)b * 2 * EG;
        const int*   es  = es_all + (size_t)b * EA;
        const int*   ed  = ed_all + (size_t)b * EA;
        float* outb = out + (size_t)b * NT * DD;

        hipMemsetAsync(dinv, 0, (size_t)ME * sizeof(float), stream);
        hipMemsetAsync(den, 0, (size_t)NT * sizeof(float), stream);

        k_deg<<<EG / 256, 256, 0, stream>>>(ei + EG, dinv);
        k_dinv<<<ME / 256, 256, 0, stream>>>(dinv);

        k_zinit<<<(ME * DD / 4) / 256, 256, 0, stream>>>(t, t2e, dinv, z);
        k_zscatter<<<(int)(((long)EG * DD) / 256), 256, 0, stream>>>(t, t2e, dinv, ei, z);

        // zb = bf16(dinv ⊙ z);   ee = zb @ Wgnn + bgnn  (bf16 MFMA)
        k_cast_rs<<<(int)(((long)ME * DD / 4) / 256), 256, 0, stream>>>(z, dinv, zb);
        gemm_bt_mfma<<<dim3(ME / 128, DD / 128), 256, 0, stream>>>(
            zb, Wgt, bgnn, ee, ME, DD, DD);

        // k/q projections (fp32, skinny N=64)
        gemm_tiled<false, true><<<dim3(ME / 64, 1), 256, 0, stream>>>(
            ee, nullptr, Wk, bk, kmat, DD, DKK);
        gemm_tiled<false, true><<<dim3(NT / 64, 1), 256, 0, stream>>>(
            t, nullptr, Wq, bq, qmat, DD, DKK);

        // zb dead -> region X becomes gatt (zero it now, NOT earlier)
        hipMemsetAsync(gl, 0, (size_t)NT * DD * sizeof(float), stream);

        k_dots<<<(int)(((long)EA * 64) / 256), 256, 0, stream>>>(kmat, qmat, es, ed, wbuf, den);
        k_att_scatter<<<(int)(((long)EA * DD) / 256), 256, 0, stream>>>(ee, wbuf, es, ed, gl);

        k_new<<<(int)(((long)NT * DD) / 256), 256, 0, stream>>>(t, gl, den, ga, outb);

        // lin = newt @ Wl + bl (bf16 MFMA), written back into gl (gatt dead after k_new)
        k_cast<<<(int)(((long)NT * DD / 4) / 256), 256, 0, stream>>>(outb, nb);
        gemm_bt_mfma<<<dim3(NT / 128, DD / 128), 256, 0, stream>>>(
            nb, Wlt, bl, gl, NT, DD, DD);

        k_final<<<(int)(((long)NT * DD) / 256), 256, 0, stream>>>(outb, gl, gb);
    }
}

// Round 4
// 975.905 us; speedup vs baseline: 2.2734x; 1.7488x over previous
//
#include <hip/hip_runtime.h>
#include <math.h>

// B=4, N=4096, M=16384, Eg=65536, Ea=65536, D=512, DK=64
#define BB 4
#define NT 4096
#define ME 16384
#define EG 65536
#define EA 65536
#define DD 512
#define DKK 64

using bf16x8 = __attribute__((ext_vector_type(8))) short;
using f32x4  = __attribute__((ext_vector_type(4))) float;
using u16x8  = __attribute__((ext_vector_type(8))) unsigned short;

// round-to-nearest-even f32 -> bf16
static __device__ __forceinline__ unsigned short f2bf(float f) {
    unsigned u = __float_as_uint(f);
    u += 0x7fffu + ((u >> 16) & 1u);
    return (unsigned short)(u >> 16);
}

// ---------------- CSR build ----------------
__global__ void k_hist(const int* __restrict__ key, int* __restrict__ cnt, int n) {
    int e = blockIdx.x * blockDim.x + threadIdx.x;
    if (e < n) atomicAdd(&cnt[key[e]], 1);
}

// single-block exclusive scan over NKEYS counters -> offs (NKEYS+1) and cursor copy
template<int NKEYS>
__global__ __launch_bounds__(1024) void k_scan(const int* __restrict__ cnt,
                                               int* __restrict__ offs,
                                               int* __restrict__ cursor) {
    constexpr int C = NKEYS / 1024;
    __shared__ int sums[1024];
    int tid = threadIdx.x;
    int local[C];
    int tot = 0;
#pragma unroll
    for (int i = 0; i < C; ++i) { local[i] = cnt[tid * C + i]; tot += local[i]; }
    sums[tid] = tot;
    __syncthreads();
    for (int d = 1; d < 1024; d <<= 1) {
        int v = (tid >= d) ? sums[tid - d] : 0;
        __syncthreads();
        sums[tid] += v;
        __syncthreads();
    }
    int run = sums[tid] - tot;  // exclusive prefix of this thread's chunk
#pragma unroll
    for (int i = 0; i < C; ++i) {
        offs[tid * C + i] = run;
        cursor[tid * C + i] = run;
        run += local[i];
    }
    if (tid == 1023) offs[NKEYS] = run;
}

__global__ void k_fill(const int* __restrict__ key, int* __restrict__ cursor,
                       int* __restrict__ csr, int n) {
    int e = blockIdx.x * blockDim.x + threadIdx.x;
    if (e < n) { int p = atomicAdd(&cursor[key[e]], 1); csr[p] = e; }
}

__global__ void k_dinv(const int* __restrict__ cnt, float* __restrict__ dinv) {
    int i = blockIdx.x * blockDim.x + threadIdx.x;
    if (i < ME) dinv[i] = rsqrtf((float)cnt[i] + 1.0f);  // +1 self loop
}

// ---------------- GCN aggregation: one wave per edge-node m ----------------
// zb[m,:] = bf16( dinv[m] * ( dinv[m]*t[t2e[m],:] + sum_{e: dst=m} dinv[src]*t[t2e[src],:] ) )
__global__ __launch_bounds__(256) void k_gcn_gather(
    const float* __restrict__ t, const int* __restrict__ t2e,
    const float* __restrict__ dinv, const int* __restrict__ offs,
    const int* __restrict__ csr, const int* __restrict__ esrc,
    unsigned short* __restrict__ zb)
{
    int m = (blockIdx.x * 256 + threadIdx.x) >> 6;
    int lane = threadIdx.x & 63;
    float dm = dinv[m];
    const float* tr = t + ((long)t2e[m] << 9) + lane * 8;
    float4 v0 = *(const float4*)tr;
    float4 v1 = *(const float4*)(tr + 4);
    float4 a0, a1;
    a0.x = dm * v0.x; a0.y = dm * v0.y; a0.z = dm * v0.z; a0.w = dm * v0.w;
    a1.x = dm * v1.x; a1.y = dm * v1.y; a1.z = dm * v1.z; a1.w = dm * v1.w;
    int beg = offs[m], end = offs[m + 1];
    for (int p = beg; p < end; ++p) {
        int e = csr[p];
        int s = esrc[e];
        float ds = dinv[s];
        const float* sr = t + ((long)t2e[s] << 9) + lane * 8;
        float4 b0 = *(const float4*)sr;
        float4 b1 = *(const float4*)(sr + 4);
        a0.x += ds * b0.x; a0.y += ds * b0.y; a0.z += ds * b0.z; a0.w += ds * b0.w;
        a1.x += ds * b1.x; a1.y += ds * b1.y; a1.z += ds * b1.z; a1.w += ds * b1.w;
    }
    u16x8 o;
    o[0] = f2bf(dm * a0.x); o[1] = f2bf(dm * a0.y); o[2] = f2bf(dm * a0.z); o[3] = f2bf(dm * a0.w);
    o[4] = f2bf(dm * a1.x); o[5] = f2bf(dm * a1.y); o[6] = f2bf(dm * a1.z); o[7] = f2bf(dm * a1.w);
    *(u16x8*)(zb + ((long)m << 9) + lane * 8) = o;
}

// ---------------- attention aggregation: one wave per token n ----------------
// outb[n,:] = t[n,:] + tanh(ga)/den * sum_{e: dst=n} w[e]*ee[src,:]   (den = sum w)
__global__ __launch_bounds__(256) void k_att_gather(
    const float* __restrict__ ee, const float* __restrict__ wbuf,
    const int* __restrict__ offs, const int* __restrict__ csr,
    const int* __restrict__ esrc, const float* __restrict__ t,
    const float* __restrict__ ga, float* __restrict__ outb)
{
    int n = (blockIdx.x * 256 + threadIdx.x) >> 6;
    int lane = threadIdx.x & 63;
    float4 a0 = {0, 0, 0, 0}, a1 = {0, 0, 0, 0};
    float den = 0.0f;
    int beg = offs[n], end = offs[n + 1];
    for (int p = beg; p < end; ++p) {
        int e = csr[p];
        int s = esrc[e];
        float w = wbuf[e];
        den += w;
        const float* sr = ee + ((long)s << 9) + lane * 8;
        float4 b0 = *(const float4*)sr;
        float4 b1 = *(const float4*)(sr + 4);
        a0.x += w * b0.x; a0.y += w * b0.y; a0.z += w * b0.z; a0.w += w * b0.w;
        a1.x += w * b1.x; a1.y += w * b1.y; a1.z += w * b1.z; a1.w += w * b1.w;
    }
    float g = tanhf(ga[0]);
    float inv = den > 0.0f ? g / den : 0.0f;
    const float* tr = t + ((long)n << 9) + lane * 8;
    float4 t0 = *(const float4*)tr;
    float4 t1 = *(const float4*)(tr + 4);
    float4 o0, o1;
    o0.x = t0.x + inv * a0.x; o0.y = t0.y + inv * a0.y; o0.z = t0.z + inv * a0.z; o0.w = t0.w + inv * a0.w;
    o1.x = t1.x + inv * a1.x; o1.y = t1.y + inv * a1.y; o1.z = t1.z + inv * a1.z; o1.w = t1.w + inv * a1.w;
    float* op = outb + ((long)n << 9) + lane * 8;
    *(float4*)op = o0;
    *(float4*)(op + 4) = o1;
}

// ---------------- casts / weights ----------------
__global__ void k_cast(const float* __restrict__ x, unsigned short* __restrict__ xb) {
    long i = (long)blockIdx.x * blockDim.x + threadIdx.x;
    float4 v = *(const float4*)(x + (i << 2));
    ushort4 o;
    o.x = f2bf(v.x); o.y = f2bf(v.y); o.z = f2bf(v.z); o.w = f2bf(v.w);
    *(ushort4*)(xb + (i << 2)) = o;
}

__global__ void k_wt(const float* __restrict__ W, unsigned short* __restrict__ Wt) {
    int i = blockIdx.x * blockDim.x + threadIdx.x;  // 512*512
    int n = i >> 9, k = i & 511;
    Wt[i] = f2bf(W[((long)k << 9) + n]);
}

// ---------------- bf16 MFMA GEMM (m97 structure): C[M,N] = A[M,K] @ Bt[N,K]^T + bias ----------------
__global__ __launch_bounds__(256) void gemm_bt_mfma(
    const unsigned short* __restrict__ A, const unsigned short* __restrict__ Bt,
    const float* __restrict__ bias, float* __restrict__ C, int M, int N, int K)
{
    __shared__ short As[128 * 32];
    __shared__ short Bs[128 * 32];
    int tid = threadIdx.x;
    int lane = tid & 63;
    int w = tid >> 6;
    int wm = w >> 1, wn = w & 1;
    int bm = blockIdx.x * 128, bn = blockIdx.y * 128;

    f32x4 acc[4][4] = {};

    int srow = tid >> 2;
    int scol = (tid & 3) * 8;
    const unsigned short* Ag0 = A + (long)(bm + srow) * K + scol;
    const unsigned short* Ag1 = A + (long)(bm + 64 + srow) * K + scol;
    const unsigned short* Bg0 = Bt + (long)(bn + srow) * K + scol;
    const unsigned short* Bg1 = Bt + (long)(bn + 64 + srow) * K + scol;

    int ar = wm * 64 + (lane & 15);
    int br = wn * 64 + (lane & 15);
    int kq = (lane >> 4) * 8;

    for (int k0 = 0; k0 < K; k0 += 32) {
        __builtin_amdgcn_global_load_lds(
            (const __attribute__((address_space(1))) unsigned int*)(Ag0 + k0),
            (__attribute__((address_space(3))) unsigned int*)(As + tid * 8), 16, 0, 0);
        __builtin_amdgcn_global_load_lds(
            (const __attribute__((address_space(1))) unsigned int*)(Ag1 + k0),
            (__attribute__((address_space(3))) unsigned int*)(As + 2048 + tid * 8), 16, 0, 0);
        __builtin_amdgcn_global_load_lds(
            (const __attribute__((address_space(1))) unsigned int*)(Bg0 + k0),
            (__attribute__((address_space(3))) unsigned int*)(Bs + tid * 8), 16, 0, 0);
        __builtin_amdgcn_global_load_lds(
            (const __attribute__((address_space(1))) unsigned int*)(Bg1 + k0),
            (__attribute__((address_space(3))) unsigned int*)(Bs + 2048 + tid * 8), 16, 0, 0);
        __syncthreads();

        bf16x8 af[4], bf[4];
#pragma unroll
        for (int rb = 0; rb < 4; ++rb)
            af[rb] = *(const bf16x8*)&As[(ar + rb * 16) * 32 + kq];
#pragma unroll
        for (int cb = 0; cb < 4; ++cb)
            bf[cb] = *(const bf16x8*)&Bs[(br + cb * 16) * 32 + kq];
#pragma unroll
        for (int rb = 0; rb < 4; ++rb)
#pragma unroll
            for (int cb = 0; cb < 4; ++cb)
                acc[rb][cb] = __builtin_amdgcn_mfma_f32_16x16x32_bf16(
                    af[rb], bf[cb], acc[rb][cb], 0, 0, 0);
        __syncthreads();
    }

#pragma unroll
    for (int rb = 0; rb < 4; ++rb) {
        int row0 = bm + wm * 64 + rb * 16 + ((lane >> 4) << 2);
#pragma unroll
        for (int cb = 0; cb < 4; ++cb) {
            int col = bn + wn * 64 + cb * 16 + (lane & 15);
            float bv = bias[col];
            float* cp = C + (long)row0 * N + col;
#pragma unroll
            for (int r = 0; r < 4; ++r)
                cp[(long)r * N] = acc[rb][cb][r] + bv;
        }
    }
}

// ---------------- fp32 tiled GEMM (skinny k/q projections) ----------------
template<bool BIAS>
__global__ void gemm_tiled(const float* __restrict__ A, const float* __restrict__ Bw,
                           const float* __restrict__ bias, float* __restrict__ C,
                           int K, int Nc) {
    __shared__ float As[16][64];
    __shared__ float Bs[16][64];
    int tid = threadIdx.x;
    int tx = tid & 15, ty = tid >> 4;
    int bm = blockIdx.x * 64, bn = blockIdx.y * 64;
    float acc[4][4] = {};
    int arow = bm + (tid >> 2);
    long aoff = (long)arow * K;
    int kk0 = (tid & 3) * 4;
    int arowl = tid >> 2;
    for (int k0 = 0; k0 < K; k0 += 16) {
        float4 av = *(const float4*)(A + aoff + k0 + kk0);
        As[kk0 + 0][arowl] = av.x;
        As[kk0 + 1][arowl] = av.y;
        As[kk0 + 2][arowl] = av.z;
        As[kk0 + 3][arowl] = av.w;
        float4 bv = *(const float4*)(Bw + (long)(k0 + (tid >> 4)) * Nc + bn + (tid & 15) * 4);
        *(float4*)&Bs[tid >> 4][(tid & 15) * 4] = bv;
        __syncthreads();
#pragma unroll
        for (int k = 0; k < 16; ++k) {
            float4 a = *(const float4*)&As[k][ty * 4];
            float4 b = *(const float4*)&Bs[k][tx * 4];
            acc[0][0] += a.x * b.x; acc[0][1] += a.x * b.y; acc[0][2] += a.x * b.z; acc[0][3] += a.x * b.w;
            acc[1][0] += a.y * b.x; acc[1][1] += a.y * b.y; acc[1][2] += a.y * b.z; acc[1][3] += a.y * b.w;
            acc[2][0] += a.z * b.x; acc[2][1] += a.z * b.y; acc[2][2] += a.z * b.z; acc[2][3] += a.z * b.w;
            acc[3][0] += a.w * b.x; acc[3][1] += a.w * b.y; acc[3][2] += a.w * b.z; acc[3][3] += a.w * b.w;
        }
        __syncthreads();
    }
#pragma unroll
    for (int i = 0; i < 4; ++i) {
        float4 v = make_float4(acc[i][0], acc[i][1], acc[i][2], acc[i][3]);
        if (BIAS) {
            const float4 bb = *(const float4*)(bias + bn + tx * 4);
            v.x += bb.x; v.y += bb.y; v.z += bb.z; v.w += bb.w;
        }
        *(float4*)(C + (long)(bm + ty * 4 + i) * Nc + bn + tx * 4) = v;
    }
}

// ---------------- attention dots ----------------
__global__ void k_dots(const float* __restrict__ kmat, const float* __restrict__ qmat,
                       const int* __restrict__ esrc, const int* __restrict__ edst,
                       float* __restrict__ wbuf) {
    long gid = (long)blockIdx.x * blockDim.x + threadIdx.x;
    int lane = (int)(gid & 63);
    long e = gid >> 6;
    if (e >= EA) return;
    int s = esrc[e], dd = edst[e];
    float p = qmat[((long)dd << 6) + lane] * kmat[((long)s << 6) + lane];
#pragma unroll
    for (int off = 32; off > 0; off >>= 1) p += __shfl_down(p, off);
    if (lane == 0) wbuf[e] = expf(p * 0.125f);  // softmax max-shift is exact no-op
}

// out += tanh(gb) * lin   (lin already has +bl)
__global__ void k_final(float* __restrict__ outb, const float* __restrict__ lin,
                        const float* __restrict__ gb) {
    long i = (long)blockIdx.x * blockDim.x + threadIdx.x;
    float g = tanhf(gb[0]);
    outb[i] = outb[i] + g * lin[i];
}

extern "C" void kernel_launch(void* const* d_in, const int* in_sizes, int n_in,
                              void* d_out, int out_size, void* d_ws, size_t ws_size,
                              hipStream_t stream) {
    const float* t_all   = (const float*)d_in[0];
    const int*   t2e_all = (const int*)d_in[1];
    const int*   ei_all  = (const int*)d_in[2];
    const int*   es_all  = (const int*)d_in[3];
    const int*   ed_all  = (const int*)d_in[4];
    const float* Wgnn    = (const float*)d_in[5];
    const float* bgnn    = (const float*)d_in[6];
    const float* Wk      = (const float*)d_in[7];
    const float* bk      = (const float*)d_in[8];
    const float* Wq      = (const float*)d_in[9];
    const float* bq      = (const float*)d_in[10];
    const float* Wl      = (const float*)d_in[11];
    const float* bl      = (const float*)d_in[12];
    const float* ga      = (const float*)d_in[13];
    const float* gb      = (const float*)d_in[14];
    float* out = (float*)d_out;

    // workspace (~71 MB peak); 16B-aligned buffers first
    char* wsb = (char*)d_ws;
    size_t off = 0;
    float* ee = (float*)(wsb + off); off += (size_t)ME * DD * 4;           // 33.5 MB
    unsigned short* zb = (unsigned short*)(wsb + off); off += (size_t)ME * DD * 2;  // 16.8 MB
    float* gl = (float*)(wsb + off); off += (size_t)NT * DD * 4;           // 8.4 MB (lin)
    unsigned short* nb = (unsigned short*)(wsb + off); off += (size_t)NT * DD * 2;  // 4.2 MB
    float* kmat = (float*)(wsb + off); off += (size_t)ME * DKK * 4;        // 4.2 MB
    float* qmat = (float*)(wsb + off); off += (size_t)NT * DKK * 4;        // 1.0 MB
    unsigned short* Wgt = (unsigned short*)(wsb + off); off += (size_t)DD * DD * 2;
    unsigned short* Wlt = (unsigned short*)(wsb + off); off += (size_t)DD * DD * 2;
    float* dinv  = (float*)(wsb + off); off += (size_t)ME * 4;
    float* wbuf  = (float*)(wsb + off); off += (size_t)EA * 4;
    int* cntG  = (int*)(wsb + off); off += (size_t)ME * 4;
    int* offsG = (int*)(wsb + off); off += (size_t)(ME + 4) * 4;
    int* curG  = (int*)(wsb + off); off += (size_t)ME * 4;
    int* csrG  = (int*)(wsb + off); off += (size_t)EG * 4;
    int* cntA  = (int*)(wsb + off); off += (size_t)NT * 4;
    int* offsA = (int*)(wsb + off); off += (size_t)(NT + 4) * 4;
    int* curA  = (int*)(wsb + off); off += (size_t)NT * 4;
    int* csrA  = (int*)(wsb + off); off += (size_t)EA * 4;

    // one-time weight transpose-casts
    k_wt<<<(DD * DD) / 256, 256, 0, stream>>>(Wgnn, Wgt);
    k_wt<<<(DD * DD) / 256, 256, 0, stream>>>(Wl, Wlt);

    for (int b = 0; b < BB; ++b) {
        const float* t   = t_all + (size_t)b * NT * DD;
        const int*   t2e = t2e_all + (size_t)b * ME;
        const int*   ei  = ei_all + (size_t)b * 2 * EG;   // src = ei[0:EG), dst = ei[EG:2EG)
        const int*   es  = es_all + (size_t)b * EA;
        const int*   ed  = ed_all + (size_t)b * EA;
        float* outb = out + (size_t)b * NT * DD;

        // ---- CSR for graph edges (dst in [0,ME)) + degrees ----
        hipMemsetAsync(cntG, 0, (size_t)ME * 4, stream);
        k_hist<<<EG / 256, 256, 0, stream>>>(ei + EG, cntG, EG);
        k_scan<ME><<<1, 1024, 0, stream>>>(cntG, offsG, curG);
        k_dinv<<<ME / 256, 256, 0, stream>>>(cntG, dinv);
        k_fill<<<EG / 256, 256, 0, stream>>>(ei + EG, curG, csrG, EG);

        // ---- CSR for attention edges (dst in [0,NT)) ----
        hipMemsetAsync(cntA, 0, (size_t)NT * 4, stream);
        k_hist<<<EA / 256, 256, 0, stream>>>(ed, cntA, EA);
        k_scan<NT><<<1, 1024, 0, stream>>>(cntA, offsA, curA);
        k_fill<<<EA / 256, 256, 0, stream>>>(ed, curA, csrA, EA);

        // ---- GCN aggregate -> zb (bf16), then ee = zb @ Wgnn + bgnn ----
        k_gcn_gather<<<(ME * 64) / 256, 256, 0, stream>>>(t, t2e, dinv, offsG, csrG, ei, zb);
        gemm_bt_mfma<<<dim3(ME / 128, DD / 128), 256, 0, stream>>>(zb, Wgt, bgnn, ee, ME, DD, DD);

        // ---- k/q projections (fp32, skinny N=64) ----
        gemm_tiled<true><<<dim3(ME / 64, 1), 256, 0, stream>>>(ee, Wk, bk, kmat, DD, DKK);
        gemm_tiled<true><<<dim3(NT / 64, 1), 256, 0, stream>>>(t, Wq, bq, qmat, DD, DKK);

        // ---- attention ----
        k_dots<<<(int)(((long)EA * 64) / 256), 256, 0, stream>>>(kmat, qmat, es, ed, wbuf);
        k_att_gather<<<(NT * 64) / 256, 256, 0, stream>>>(ee, wbuf, offsA, csrA, es, t, ga, outb);

        // ---- final linear + residual ----
        k_cast<<<(int)(((long)NT * DD / 4) / 256), 256, 0, stream>>>(outb, nb);
        gemm_bt_mfma<<<dim3(NT / 128, DD / 128), 256, 0, stream>>>(nb, Wlt, bl, gl, NT, DD, DD);
        k_final<<<(int)(((long)NT * DD) / 256), 256, 0, stream>>>(outb, gl, gb);
    }
}

// Round 5
// 851.573 us; speedup vs baseline: 2.6053x; 1.1460x over previous
//
#include <hip/hip_runtime.h>
#include <math.h>

// B=4, N=4096, M=16384, Eg=65536, Ea=65536, D=512, DK=64
#define BB 4
#define NT 4096
#define ME 16384
#define EG 65536
#define EA 65536
#define DD 512
#define DKK 64

using bf16x8 = __attribute__((ext_vector_type(8))) short;
using f32x4  = __attribute__((ext_vector_type(4))) float;

// round-to-nearest-even f32 -> bf16
static __device__ __forceinline__ unsigned short f2bf(float f) {
    unsigned u = __float_as_uint(f);
    u += 0x7fffu + ((u >> 16) & 1u);
    return (unsigned short)(u >> 16);
}
static __device__ __forceinline__ float bf2f(unsigned short u) {
    return __uint_as_float((unsigned)u << 16);
}
// a[0..7] += s * unpack8(v)
static __device__ __forceinline__ void acc8(float* a, uint4 v, float s) {
    a[0] += s * __uint_as_float(v.x << 16);
    a[1] += s * __uint_as_float(v.x & 0xffff0000u);
    a[2] += s * __uint_as_float(v.y << 16);
    a[3] += s * __uint_as_float(v.y & 0xffff0000u);
    a[4] += s * __uint_as_float(v.z << 16);
    a[5] += s * __uint_as_float(v.z & 0xffff0000u);
    a[6] += s * __uint_as_float(v.w << 16);
    a[7] += s * __uint_as_float(v.w & 0xffff0000u);
}
static __device__ __forceinline__ uint4 pack8(const float* a) {
    uint4 o;
    o.x = (unsigned)f2bf(a[0]) | ((unsigned)f2bf(a[1]) << 16);
    o.y = (unsigned)f2bf(a[2]) | ((unsigned)f2bf(a[3]) << 16);
    o.z = (unsigned)f2bf(a[4]) | ((unsigned)f2bf(a[5]) << 16);
    o.w = (unsigned)f2bf(a[6]) | ((unsigned)f2bf(a[7]) << 16);
    return o;
}

// ---------------- combined CSR build ----------------
__global__ void k_hist2(const int* __restrict__ gdst, const int* __restrict__ adst,
                        int* __restrict__ cntG, int* __restrict__ cntA) {
    int e = blockIdx.x * 256 + threadIdx.x;
    if (e < EG) atomicAdd(&cntG[gdst[e]], 1);
    else if (e - EG < EA) atomicAdd(&cntA[adst[e - EG]], 1);
}

// block 0: scan cntG (ME) -> offsG/curG + dinv ; block 1: scan cntA (NT) -> offsA/curA
__global__ __launch_bounds__(1024) void k_scan2(
    const int* __restrict__ cntG, int* __restrict__ offsG, int* __restrict__ curG,
    float* __restrict__ dinv,
    const int* __restrict__ cntA, int* __restrict__ offsA, int* __restrict__ curA) {
    __shared__ int sums[1024];
    int tid = threadIdx.x;
    const int* cnt;
    int *offs, *cur;
    int C, nk;
    if (blockIdx.x == 0) { cnt = cntG; offs = offsG; cur = curG; C = ME / 1024; nk = ME; }
    else                 { cnt = cntA; offs = offsA; cur = curA; C = NT / 1024; nk = NT; }
    int local[16];
    int tot = 0;
    for (int i = 0; i < C; ++i) { local[i] = cnt[tid * C + i]; tot += local[i]; }
    sums[tid] = tot;
    __syncthreads();
    for (int d = 1; d < 1024; d <<= 1) {
        int v = (tid >= d) ? sums[tid - d] : 0;
        __syncthreads();
        sums[tid] += v;
        __syncthreads();
    }
    int run = sums[tid] - tot;
    for (int i = 0; i < C; ++i) {
        int idx = tid * C + i;
        offs[idx] = run;
        cur[idx] = run;
        if (blockIdx.x == 0) dinv[idx] = rsqrtf((float)local[i] + 1.0f);  // +1 self loop
        run += local[i];
    }
    if (tid == 1023) offs[nk] = run;
}

__global__ void k_fill2(const int* __restrict__ gdst, const int* __restrict__ adst,
                        int* __restrict__ curG, int* __restrict__ csrG,
                        int* __restrict__ curA, int* __restrict__ csrA) {
    int e = blockIdx.x * 256 + threadIdx.x;
    if (e < EG) { int p = atomicAdd(&curG[gdst[e]], 1); csrG[p] = e; }
    else if (e - EG < EA) { int e2 = e - EG; int p = atomicAdd(&curA[adst[e2]], 1); csrA[p] = e2; }
}

// ---------------- casts / weight prep ----------------
__global__ void k_cast(const float* __restrict__ x, unsigned short* __restrict__ xb) {
    long i = (long)blockIdx.x * blockDim.x + threadIdx.x;
    float4 v = *(const float4*)(x + (i << 2));
    ushort4 o;
    o.x = f2bf(v.x); o.y = f2bf(v.y); o.z = f2bf(v.z); o.w = f2bf(v.w);
    *(ushort4*)(xb + (i << 2)) = o;
}

// Wt[n][k] = bf16(W[k][n]), W is [512 x 512]
__global__ void k_wt(const float* __restrict__ W, unsigned short* __restrict__ Wt) {
    int i = blockIdx.x * blockDim.x + threadIdx.x;
    int n = i >> 9, k = i & 511;
    Wt[i] = f2bf(W[((long)k << 9) + n]);
}
// Wt[n][k] = bf16(W[k][n]), W is [512 x 64]
__global__ void k_wt64(const float* __restrict__ W, unsigned short* __restrict__ Wt) {
    int i = blockIdx.x * blockDim.x + threadIdx.x;  // 64*512
    int n = i >> 9, k = i & 511;
    Wt[i] = f2bf(W[k * 64 + n]);
}
// bgk[n] = bk[n] + sum_k bgnn[k]*Wk[k][n]
__global__ void k_bgk(const float* __restrict__ bgnn, const float* __restrict__ Wk,
                      const float* __restrict__ bk, float* __restrict__ bgk) {
    int n = threadIdx.x;  // 64 threads
    float s = bk[n];
    for (int k = 0; k < DD; ++k) s += bgnn[k] * Wk[k * 64 + n];
    bgk[n] = s;
}

// ---------------- GCN aggregation: one wave per edge-node m (bf16 t reads) ----------------
// zb[m,:] = bf16( dinv[m] * ( dinv[m]*t[t2e[m],:] + sum_{e: dst=m} dinv[src]*t[t2e[src],:] ) )
__global__ __launch_bounds__(256) void k_gcn_gather(
    const unsigned short* __restrict__ tb, const int* __restrict__ t2e,
    const float* __restrict__ dinv, const int* __restrict__ offs,
    const int* __restrict__ csr, const int* __restrict__ esrc,
    unsigned short* __restrict__ zb)
{
    int m = (blockIdx.x * 256 + threadIdx.x) >> 6;
    int lane = threadIdx.x & 63;
    float dm = dinv[m];
    float a[8] = {0, 0, 0, 0, 0, 0, 0, 0};
    acc8(a, *(const uint4*)(tb + ((long)t2e[m] << 9) + lane * 8), dm);
    int beg = offs[m], end = offs[m + 1];
    for (int p = beg; p < end; ++p) {
        int e = csr[p];
        int s = esrc[e];
        acc8(a, *(const uint4*)(tb + ((long)t2e[s] << 9) + lane * 8), dinv[s]);
    }
#pragma unroll
    for (int j = 0; j < 8; ++j) a[j] *= dm;
    *(uint4*)(zb + ((long)m << 9) + lane * 8) = pack8(a);
}

// ---------------- attention aggregation: one wave per token n ----------------
// outb[n,:] = t[n,:] + tanh(ga)/den * sum w[e]*ee[src,:];  nb = bf16(outb)
__global__ __launch_bounds__(256) void k_att_gather(
    const unsigned short* __restrict__ eeb, const float* __restrict__ wbuf,
    const int* __restrict__ offs, const int* __restrict__ csr,
    const int* __restrict__ esrc, const float* __restrict__ t,
    const float* __restrict__ ga, float* __restrict__ outb,
    unsigned short* __restrict__ nb)
{
    int n = (blockIdx.x * 256 + threadIdx.x) >> 6;
    int lane = threadIdx.x & 63;
    float a[8] = {0, 0, 0, 0, 0, 0, 0, 0};
    float den = 0.0f;
    int beg = offs[n], end = offs[n + 1];
    for (int p = beg; p < end; ++p) {
        int e = csr[p];
        int s = esrc[e];
        float w = wbuf[e];
        den += w;
        acc8(a, *(const uint4*)(eeb + ((long)s << 9) + lane * 8), w);
    }
    float g = tanhf(ga[0]);
    float inv = den > 0.0f ? g / den : 0.0f;
    const float* tr = t + ((long)n << 9) + lane * 8;
    float4 t0 = *(const float4*)tr;
    float4 t1 = *(const float4*)(tr + 4);
    float o[8];
    o[0] = t0.x + inv * a[0]; o[1] = t0.y + inv * a[1];
    o[2] = t0.z + inv * a[2]; o[3] = t0.w + inv * a[3];
    o[4] = t1.x + inv * a[4]; o[5] = t1.y + inv * a[5];
    o[6] = t1.z + inv * a[6]; o[7] = t1.w + inv * a[7];
    float* op = outb + ((long)n << 9) + lane * 8;
    *(float4*)op = make_float4(o[0], o[1], o[2], o[3]);
    *(float4*)(op + 4) = make_float4(o[4], o[5], o[6], o[7]);
    *(uint4*)(nb + ((long)n << 9) + lane * 8) = pack8(o);
}

// ---------------- bf16 MFMA GEMM 128x128 (m97 structure), two epilogues ----------------
// MODE 0: Cb(bf16) = A@Bt^T + bias.   MODE 1: Cf(f32) += tanh(gs[0]) * (A@Bt^T + bias)
template<int MODE>
__global__ __launch_bounds__(256) void gemm_bt128(
    const unsigned short* __restrict__ A, const unsigned short* __restrict__ Bt,
    const float* __restrict__ bias, unsigned short* __restrict__ Cb,
    float* __restrict__ Cf, const float* __restrict__ gs, int M, int N, int K)
{
    __shared__ short As[128 * 32];
    __shared__ short Bs[128 * 32];
    int tid = threadIdx.x;
    int lane = tid & 63;
    int w = tid >> 6;
    int wm = w >> 1, wn = w & 1;
    int bm = blockIdx.x * 128, bn = blockIdx.y * 128;

    f32x4 acc[4][4] = {};

    int srow = tid >> 2;
    int scol = (tid & 3) * 8;
    const unsigned short* Ag0 = A + (long)(bm + srow) * K + scol;
    const unsigned short* Ag1 = A + (long)(bm + 64 + srow) * K + scol;
    const unsigned short* Bg0 = Bt + (long)(bn + srow) * K + scol;
    const unsigned short* Bg1 = Bt + (long)(bn + 64 + srow) * K + scol;

    int ar = wm * 64 + (lane & 15);
    int br = wn * 64 + (lane & 15);
    int kq = (lane >> 4) * 8;

    for (int k0 = 0; k0 < K; k0 += 32) {
        __builtin_amdgcn_global_load_lds(
            (const __attribute__((address_space(1))) unsigned int*)(Ag0 + k0),
            (__attribute__((address_space(3))) unsigned int*)(As + tid * 8), 16, 0, 0);
        __builtin_amdgcn_global_load_lds(
            (const __attribute__((address_space(1))) unsigned int*)(Ag1 + k0),
            (__attribute__((address_space(3))) unsigned int*)(As + 2048 + tid * 8), 16, 0, 0);
        __builtin_amdgcn_global_load_lds(
            (const __attribute__((address_space(1))) unsigned int*)(Bg0 + k0),
            (__attribute__((address_space(3))) unsigned int*)(Bs + tid * 8), 16, 0, 0);
        __builtin_amdgcn_global_load_lds(
            (const __attribute__((address_space(1))) unsigned int*)(Bg1 + k0),
            (__attribute__((address_space(3))) unsigned int*)(Bs + 2048 + tid * 8), 16, 0, 0);
        __syncthreads();

        bf16x8 af[4], bf[4];
#pragma unroll
        for (int rb = 0; rb < 4; ++rb)
            af[rb] = *(const bf16x8*)&As[(ar + rb * 16) * 32 + kq];
#pragma unroll
        for (int cb = 0; cb < 4; ++cb)
            bf[cb] = *(const bf16x8*)&Bs[(br + cb * 16) * 32 + kq];
#pragma unroll
        for (int rb = 0; rb < 4; ++rb)
#pragma unroll
            for (int cb = 0; cb < 4; ++cb)
                acc[rb][cb] = __builtin_amdgcn_mfma_f32_16x16x32_bf16(
                    af[rb], bf[cb], acc[rb][cb], 0, 0, 0);
        __syncthreads();
    }

    float g = (MODE == 1) ? tanhf(gs[0]) : 0.0f;
#pragma unroll
    for (int rb = 0; rb < 4; ++rb) {
        int row0 = bm + wm * 64 + rb * 16 + ((lane >> 4) << 2);
#pragma unroll
        for (int cb = 0; cb < 4; ++cb) {
            int col = bn + wn * 64 + cb * 16 + (lane & 15);
            float bv = bias[col];
#pragma unroll
            for (int r = 0; r < 4; ++r) {
                long idx = (long)(row0 + r) * N + col;
                if (MODE == 0) Cb[idx] = f2bf(acc[rb][cb][r] + bv);
                else           Cf[idx] += g * (acc[rb][cb][r] + bv);
            }
        }
    }
}

// ---------------- bf16 MFMA skinny GEMM: Cb[M,64] = A[M,512] @ Bt[64,512]^T + bias ----------------
// tile 128x64, 256 threads = 4 waves; wave w: rows w*32..w*32+31, all 64 cols.
__global__ __launch_bounds__(256) void gemm_bt_n64(
    const unsigned short* __restrict__ A, const unsigned short* __restrict__ Bt,
    const float* __restrict__ bias, unsigned short* __restrict__ Cb, int M)
{
    __shared__ short As[128 * 32];
    __shared__ short Bs[64 * 32];
    int tid = threadIdx.x;
    int lane = tid & 63;
    int w = tid >> 6;
    int bm = blockIdx.x * 128;

    f32x4 acc[2][4] = {};

    int srow = tid >> 2;
    int scol = (tid & 3) * 8;
    const unsigned short* Ag0 = A + (long)(bm + srow) * DD + scol;
    const unsigned short* Ag1 = A + (long)(bm + 64 + srow) * DD + scol;
    const unsigned short* Bg = Bt + (long)srow * DD + scol;

    int ar = w * 32 + (lane & 15);
    int br = (lane & 15);
    int kq = (lane >> 4) * 8;

    for (int k0 = 0; k0 < DD; k0 += 32) {
        __builtin_amdgcn_global_load_lds(
            (const __attribute__((address_space(1))) unsigned int*)(Ag0 + k0),
            (__attribute__((address_space(3))) unsigned int*)(As + tid * 8), 16, 0, 0);
        __builtin_amdgcn_global_load_lds(
            (const __attribute__((address_space(1))) unsigned int*)(Ag1 + k0),
            (__attribute__((address_space(3))) unsigned int*)(As + 2048 + tid * 8), 16, 0, 0);
        __builtin_amdgcn_global_load_lds(
            (const __attribute__((address_space(1))) unsigned int*)(Bg + k0),
            (__attribute__((address_space(3))) unsigned int*)(Bs + tid * 8), 16, 0, 0);
        __syncthreads();

        bf16x8 af[2], bf[4];
#pragma unroll
        for (int rb = 0; rb < 2; ++rb)
            af[rb] = *(const bf16x8*)&As[(ar + rb * 16) * 32 + kq];
#pragma unroll
        for (int cb = 0; cb < 4; ++cb)
            bf[cb] = *(const bf16x8*)&Bs[(br + cb * 16) * 32 + kq];
#pragma unroll
        for (int rb = 0; rb < 2; ++rb)
#pragma unroll
            for (int cb = 0; cb < 4; ++cb)
                acc[rb][cb] = __builtin_amdgcn_mfma_f32_16x16x32_bf16(
                    af[rb], bf[cb], acc[rb][cb], 0, 0, 0);
        __syncthreads();
    }

#pragma unroll
    for (int rb = 0; rb < 2; ++rb) {
        int row0 = bm + w * 32 + rb * 16 + ((lane >> 4) << 2);
#pragma unroll
        for (int cb = 0; cb < 4; ++cb) {
            int col = cb * 16 + (lane & 15);
            float bv = bias[col];
#pragma unroll
            for (int r = 0; r < 4; ++r)
                Cb[(long)(row0 + r) * DKK + col] = f2bf(acc[rb][cb][r] + bv);
        }
    }
}

// ---------------- fp32 tiled GEMM (one-time Wgk = Wgnn @ Wk) ----------------
__global__ void gemm_tiled(const float* __restrict__ A, const float* __restrict__ Bw,
                           float* __restrict__ C, int K, int Nc) {
    __shared__ float As[16][64];
    __shared__ float Bs[16][64];
    int tid = threadIdx.x;
    int tx = tid & 15, ty = tid >> 4;
    int bm = blockIdx.x * 64, bn = blockIdx.y * 64;
    float acc[4][4] = {};
    int arow = bm + (tid >> 2);
    long aoff = (long)arow * K;
    int kk0 = (tid & 3) * 4;
    int arowl = tid >> 2;
    for (int k0 = 0; k0 < K; k0 += 16) {
        float4 av = *(const float4*)(A + aoff + k0 + kk0);
        As[kk0 + 0][arowl] = av.x;
        As[kk0 + 1][arowl] = av.y;
        As[kk0 + 2][arowl] = av.z;
        As[kk0 + 3][arowl] = av.w;
        float4 bv = *(const float4*)(Bw + (long)(k0 + (tid >> 4)) * Nc + bn + (tid & 15) * 4);
        *(float4*)&Bs[tid >> 4][(tid & 15) * 4] = bv;
        __syncthreads();
#pragma unroll
        for (int k = 0; k < 16; ++k) {
            float4 a = *(const float4*)&As[k][ty * 4];
            float4 b = *(const float4*)&Bs[k][tx * 4];
            acc[0][0] += a.x * b.x; acc[0][1] += a.x * b.y; acc[0][2] += a.x * b.z; acc[0][3] += a.x * b.w;
            acc[1][0] += a.y * b.x; acc[1][1] += a.y * b.y; acc[1][2] += a.y * b.z; acc[1][3] += a.y * b.w;
            acc[2][0] += a.z * b.x; acc[2][1] += a.z * b.y; acc[2][2] += a.z * b.z; acc[2][3] += a.z * b.w;
            acc[3][0] += a.w * b.x; acc[3][1] += a.w * b.y; acc[3][2] += a.w * b.z; acc[3][3] += a.w * b.w;
        }
        __syncthreads();
    }
#pragma unroll
    for (int i = 0; i < 4; ++i)
        *(float4*)(C + (long)(bm + ty * 4 + i) * Nc + bn + tx * 4) =
            make_float4(acc[i][0], acc[i][1], acc[i][2], acc[i][3]);
}

// ---------------- attention dots (bf16 k/q) ----------------
__global__ void k_dots(const unsigned short* __restrict__ kb, const unsigned short* __restrict__ qb,
                       const int* __restrict__ esrc, const int* __restrict__ edst,
                       float* __restrict__ wbuf) {
    int e = (blockIdx.x * 256 + threadIdx.x) >> 6;
    int lane = threadIdx.x & 63;
    int s = esrc[e], dd = edst[e];
    float p = bf2f(qb[((long)dd << 6) + lane]) * bf2f(kb[((long)s << 6) + lane]);
#pragma unroll
    for (int off = 32; off > 0; off >>= 1) p += __shfl_down(p, off);
    if (lane == 0) wbuf[e] = expf(p * 0.125f);  // softmax max-shift is exact no-op
}

extern "C" void kernel_launch(void* const* d_in, const int* in_sizes, int n_in,
                              void* d_out, int out_size, void* d_ws, size_t ws_size,
                              hipStream_t stream) {
    const float* t_all   = (const float*)d_in[0];
    const int*   t2e_all = (const int*)d_in[1];
    const int*   ei_all  = (const int*)d_in[2];
    const int*   es_all  = (const int*)d_in[3];
    const int*   ed_all  = (const int*)d_in[4];
    const float* Wgnn    = (const float*)d_in[5];
    const float* bgnn    = (const float*)d_in[6];
    const float* Wk      = (const float*)d_in[7];
    const float* bk      = (const float*)d_in[8];
    const float* Wq      = (const float*)d_in[9];
    const float* bq      = (const float*)d_in[10];
    const float* Wl      = (const float*)d_in[11];
    const float* bl      = (const float*)d_in[12];
    const float* ga      = (const float*)d_in[13];
    const float* gb      = (const float*)d_in[14];
    float* out = (float*)d_out;

    // workspace (~46 MB peak)
    char* wsb = (char*)d_ws;
    size_t off = 0;
    unsigned short* eeb   = (unsigned short*)(wsb + off); off += (size_t)ME * DD * 2;  // 16.8 MB
    unsigned short* zb    = (unsigned short*)(wsb + off); off += (size_t)ME * DD * 2;  // 16.8 MB
    unsigned short* tb    = (unsigned short*)(wsb + off); off += (size_t)NT * DD * 2;  // 4.2 MB
    unsigned short* nb    = (unsigned short*)(wsb + off); off += (size_t)NT * DD * 2;  // 4.2 MB
    unsigned short* kmatb = (unsigned short*)(wsb + off); off += (size_t)ME * DKK * 2; // 2.1 MB
    unsigned short* qmatb = (unsigned short*)(wsb + off); off += (size_t)NT * DKK * 2; // 0.5 MB
    unsigned short* Wgt   = (unsigned short*)(wsb + off); off += (size_t)DD * DD * 2;
    unsigned short* Wlt   = (unsigned short*)(wsb + off); off += (size_t)DD * DD * 2;
    unsigned short* Wqt   = (unsigned short*)(wsb + off); off += (size_t)DKK * DD * 2;
    unsigned short* Wgkt  = (unsigned short*)(wsb + off); off += (size_t)DKK * DD * 2;
    float* Wgk  = (float*)(wsb + off); off += (size_t)DD * DKK * 4;
    float* bgk  = (float*)(wsb + off); off += 64 * 4;
    float* dinv = (float*)(wsb + off); off += (size_t)ME * 4;
    float* wbuf = (float*)(wsb + off); off += (size_t)EA * 4;
    int* cntG  = (int*)(wsb + off); off += (size_t)ME * 4;   // cntG/cntA contiguous -> one memset
    int* cntA  = (int*)(wsb + off); off += (size_t)NT * 4;
    int* offsG = (int*)(wsb + off); off += (size_t)(ME + 4) * 4;
    int* curG  = (int*)(wsb + off); off += (size_t)ME * 4;
    int* csrG  = (int*)(wsb + off); off += (size_t)EG * 4;
    int* offsA = (int*)(wsb + off); off += (size_t)(NT + 4) * 4;
    int* curA  = (int*)(wsb + off); off += (size_t)NT * 4;
    int* csrA  = (int*)(wsb + off); off += (size_t)EA * 4;

    // ---- one-time weight prep ----
    k_wt<<<(DD * DD) / 256, 256, 0, stream>>>(Wgnn, Wgt);
    k_wt<<<(DD * DD) / 256, 256, 0, stream>>>(Wl, Wlt);
    k_wt64<<<(DKK * DD) / 256, 256, 0, stream>>>(Wq, Wqt);
    gemm_tiled<<<dim3(DD / 64, 1), 256, 0, stream>>>(Wgnn, Wk, Wgk, DD, DKK);  // Wgk = Wgnn@Wk
    k_bgk<<<1, 64, 0, stream>>>(bgnn, Wk, bk, bgk);
    k_wt64<<<(DKK * DD) / 256, 256, 0, stream>>>(Wgk, Wgkt);

    for (int b = 0; b < BB; ++b) {
        const float* t   = t_all + (size_t)b * NT * DD;
        const int*   t2e = t2e_all + (size_t)b * ME;
        const int*   ei  = ei_all + (size_t)b * 2 * EG;   // src = ei[0:EG), dst = ei[EG:2EG)
        const int*   es  = es_all + (size_t)b * EA;
        const int*   ed  = ed_all + (size_t)b * EA;
        float* outb = out + (size_t)b * NT * DD;

        // CSR builds (combined)
        hipMemsetAsync(cntG, 0, (size_t)(ME + NT) * 4, stream);
        k_hist2<<<(EG + EA) / 256, 256, 0, stream>>>(ei + EG, ed, cntG, cntA);
        k_scan2<<<2, 1024, 0, stream>>>(cntG, offsG, curG, dinv, cntA, offsA, curA);
        k_fill2<<<(EG + EA) / 256, 256, 0, stream>>>(ei + EG, ed, curG, csrG, curA, csrA);

        // bf16 copy of t (L2-resident gather source; also q-proj input)
        k_cast<<<(int)(((long)NT * DD / 4) / 256), 256, 0, stream>>>(t, tb);

        // GCN aggregate -> zb, then eeb = bf16(zb @ Wgnn + bgnn)
        k_gcn_gather<<<(ME * 64) / 256, 256, 0, stream>>>(tb, t2e, dinv, offsG, csrG, ei, zb);
        gemm_bt128<0><<<dim3(ME / 128, DD / 128), 256, 0, stream>>>(
            zb, Wgt, bgnn, eeb, nullptr, nullptr, ME, DD, DD);

        // fused k = zb @ (Wgnn·Wk) + (bgnn·Wk + bk);  q = tb @ Wq + bq
        gemm_bt_n64<<<ME / 128, 256, 0, stream>>>(zb, Wgkt, bgk, kmatb, ME);
        gemm_bt_n64<<<NT / 128, 256, 0, stream>>>(tb, Wqt, bq, qmatb, NT);

        // attention
        k_dots<<<(EA * 64) / 256, 256, 0, stream>>>(kmatb, qmatb, es, ed, wbuf);
        k_att_gather<<<(NT * 64) / 256, 256, 0, stream>>>(eeb, wbuf, offsA, csrA, es, t, ga, outb, nb);

        // final: outb += tanh(gb) * (nb @ Wl + bl)
        gemm_bt128<1><<<dim3(NT / 128, DD / 128), 256, 0, stream>>>(
            nb, Wlt, bl, nullptr, outb, gb, NT, DD, DD);
    }
}

// Round 6
// 539.160 us; speedup vs baseline: 4.1149x; 1.5794x over previous
//
#include <hip/hip_runtime.h>
#include <math.h>

// B=4, N=4096, M=16384, Eg=65536, Ea=65536, D=512, DK=64
#define BB 4
#define NT 4096
#define ME 16384
#define EG 65536
#define EA 65536
#define DD 512
#define DKK 64

using bf16x8 = __attribute__((ext_vector_type(8))) short;
using f32x4  = __attribute__((ext_vector_type(4))) float;

static __device__ __forceinline__ unsigned short f2bf(float f) {
    unsigned u = __float_as_uint(f);
    u += 0x7fffu + ((u >> 16) & 1u);
    return (unsigned short)(u >> 16);
}
static __device__ __forceinline__ float bf2f(unsigned short u) {
    return __uint_as_float((unsigned)u << 16);
}
static __device__ __forceinline__ void acc8(float* a, uint4 v, float s) {
    a[0] += s * __uint_as_float(v.x << 16);
    a[1] += s * __uint_as_float(v.x & 0xffff0000u);
    a[2] += s * __uint_as_float(v.y << 16);
    a[3] += s * __uint_as_float(v.y & 0xffff0000u);
    a[4] += s * __uint_as_float(v.z << 16);
    a[5] += s * __uint_as_float(v.z & 0xffff0000u);
    a[6] += s * __uint_as_float(v.w << 16);
    a[7] += s * __uint_as_float(v.w & 0xffff0000u);
}
static __device__ __forceinline__ uint4 pack8(const float* a) {
    uint4 o;
    o.x = (unsigned)f2bf(a[0]) | ((unsigned)f2bf(a[1]) << 16);
    o.y = (unsigned)f2bf(a[2]) | ((unsigned)f2bf(a[3]) << 16);
    o.z = (unsigned)f2bf(a[4]) | ((unsigned)f2bf(a[5]) << 16);
    o.w = (unsigned)f2bf(a[6]) | ((unsigned)f2bf(a[7]) << 16);
    return o;
}

// ---------------- batched CSR build ----------------
// i < B*EG: graph edge (b = i>>16); else attention edge.
__global__ void k_hist2(const int* __restrict__ ei_all, const int* __restrict__ ed_all,
                        int* __restrict__ cntG, int* __restrict__ cntA) {
    int i = blockIdx.x * 256 + threadIdx.x;
    if (i < BB * EG) {
        int b = i >> 16, e = i & (EG - 1);
        int dst = ei_all[(size_t)b * 2 * EG + EG + e];
        atomicAdd(&cntG[b * ME + dst], 1);
    } else {
        int j = i - BB * EG;            // [0, B*EA)
        atomicAdd(&cntA[(j >> 16) * NT + ed_all[j]], 1);
    }
}

// blocks 0..3: graph scan for sample b (ME keys, +dinv); blocks 4..7: attention scan (NT keys)
__global__ __launch_bounds__(1024) void k_scan2(
    const int* __restrict__ cntG, int* __restrict__ offsG, int* __restrict__ curG,
    float* __restrict__ dinv,
    const int* __restrict__ cntA, int* __restrict__ offsA, int* __restrict__ curA) {
    __shared__ int sums[1024];
    int tid = threadIdx.x;
    int bid = blockIdx.x;
    const int* cnt;
    int *offs, *cur;
    float* dv = nullptr;
    int C, nk;
    if (bid < BB) {
        cnt = cntG + bid * ME; offs = offsG + bid * (ME + 1); cur = curG + bid * ME;
        dv = dinv + bid * ME; C = ME / 1024; nk = ME;
    } else {
        int b = bid - BB;
        cnt = cntA + b * NT; offs = offsA + b * (NT + 1); cur = curA + b * NT;
        C = NT / 1024; nk = NT;
    }
    int local[16];
    int tot = 0;
    for (int i = 0; i < C; ++i) { local[i] = cnt[tid * C + i]; tot += local[i]; }
    sums[tid] = tot;
    __syncthreads();
    for (int d = 1; d < 1024; d <<= 1) {
        int v = (tid >= d) ? sums[tid - d] : 0;
        __syncthreads();
        sums[tid] += v;
        __syncthreads();
    }
    int run = sums[tid] - tot;
    for (int i = 0; i < C; ++i) {
        int idx = tid * C + i;
        offs[idx] = run;
        cur[idx] = run;
        if (dv) dv[idx] = rsqrtf((float)local[i] + 1.0f);  // +1 self loop
        run += local[i];
    }
    if (tid == 1023) offs[nk] = run;
}

__global__ void k_fill2(const int* __restrict__ ei_all, const int* __restrict__ ed_all,
                        int* __restrict__ curG, int* __restrict__ csrG,
                        int* __restrict__ curA, int* __restrict__ csrA) {
    int i = blockIdx.x * 256 + threadIdx.x;
    if (i < BB * EG) {
        int b = i >> 16, e = i & (EG - 1);
        int dst = ei_all[(size_t)b * 2 * EG + EG + e];
        int p = atomicAdd(&curG[b * ME + dst], 1);
        csrG[(size_t)b * EG + p] = e;           // local edge id
    } else {
        int j = i - BB * EG;
        int b = j >> 16, e = j & (EA - 1);
        int p = atomicAdd(&curA[b * NT + ed_all[j]], 1);
        csrA[(size_t)b * EA + p] = e;
    }
}

// ---------------- casts / weight prep ----------------
__global__ void k_cast(const float* __restrict__ x, unsigned short* __restrict__ xb) {
    long i = (long)blockIdx.x * blockDim.x + threadIdx.x;
    float4 v = *(const float4*)(x + (i << 2));
    ushort4 o;
    o.x = f2bf(v.x); o.y = f2bf(v.y); o.z = f2bf(v.z); o.w = f2bf(v.w);
    *(ushort4*)(xb + (i << 2)) = o;
}

// two 512x512 transposes in one launch: grid.y selects (Wgnn->Wgt) or (Wl->Wlt)
__global__ void k_wt2(const float* __restrict__ W0, unsigned short* __restrict__ T0,
                      const float* __restrict__ W1, unsigned short* __restrict__ T1) {
    int i = blockIdx.x * 256 + threadIdx.x;
    int n = i >> 9, k = i & 511;
    if (blockIdx.y == 0) T0[i] = f2bf(W0[((long)k << 9) + n]);
    else                 T1[i] = f2bf(W1[((long)k << 9) + n]);
}
// [512x64] transpose-cast
__global__ void k_wt64(const float* __restrict__ W, unsigned short* __restrict__ Wt) {
    int i = blockIdx.x * 256 + threadIdx.x;  // 64*512
    int n = i >> 9, k = i & 511;
    Wt[i] = f2bf(W[k * 64 + n]);
}
// bgk[n] = bk[n] + sum_k bgnn[k]*Wk[k][n]
__global__ void k_bgk(const float* __restrict__ bgnn, const float* __restrict__ Wk,
                      const float* __restrict__ bk, float* __restrict__ bgk) {
    int n = threadIdx.x;  // 64
    float s = bk[n];
    for (int k = 0; k < DD; ++k) s += bgnn[k] * Wk[k * 64 + n];
    bgk[n] = s;
}

// ---------------- GCN aggregation (batched): one wave per (b, m) ----------------
__global__ __launch_bounds__(256) void k_gcn_gather(
    const unsigned short* __restrict__ tb, const int* __restrict__ t2e_all,
    const float* __restrict__ dinv, const int* __restrict__ offsG,
    const int* __restrict__ csrG, const int* __restrict__ ei_all,
    unsigned short* __restrict__ zb)
{
    int mg = (blockIdx.x * 256 + threadIdx.x) >> 6;   // [0, B*ME)
    int lane = threadIdx.x & 63;
    int b = mg >> 14;
    int m = mg & (ME - 1);
    const float* dv = dinv + b * ME;
    const int* offs = offsG + b * (ME + 1);
    const int* csr = csrG + (size_t)b * EG;
    const int* esrc = ei_all + (size_t)b * 2 * EG;
    const unsigned short* tbb = tb + ((size_t)b * NT << 9);

    float dm = dv[m];
    float a[8] = {0, 0, 0, 0, 0, 0, 0, 0};
    acc8(a, *(const uint4*)(tbb + ((long)t2e_all[mg] << 9) + lane * 8), dm);
    int beg = offs[m], end = offs[m + 1];
    for (int p = beg; p < end; ++p) {
        int s = esrc[csr[p]];
        acc8(a, *(const uint4*)(tbb + ((long)t2e_all[(b << 14) + s] << 9) + lane * 8), dv[s]);
    }
#pragma unroll
    for (int j = 0; j < 8; ++j) a[j] *= dm;
    *(uint4*)(zb + ((long)mg << 9) + lane * 8) = pack8(a);
}

// ---------------- attention aggregation (batched): one wave per (b, n) ----------------
__global__ __launch_bounds__(256) void k_att_gather(
    const unsigned short* __restrict__ eeb, const float* __restrict__ wbuf,
    const int* __restrict__ offsA, const int* __restrict__ csrA,
    const int* __restrict__ es_all, const float* __restrict__ t_all,
    const float* __restrict__ ga, float* __restrict__ out,
    unsigned short* __restrict__ nb)
{
    int ng = (blockIdx.x * 256 + threadIdx.x) >> 6;   // [0, B*NT)
    int lane = threadIdx.x & 63;
    int b = ng >> 12;
    int n = ng & (NT - 1);
    const int* offs = offsA + b * (NT + 1);
    const int* csr = csrA + (size_t)b * EA;
    const int* esrc = es_all + (size_t)b * EA;
    const float* wb = wbuf + (size_t)b * EA;
    const unsigned short* eebb = eeb + ((size_t)b * ME << 9);

    float a[8] = {0, 0, 0, 0, 0, 0, 0, 0};
    float den = 0.0f;
    int beg = offs[n], end = offs[n + 1];
    for (int p = beg; p < end; ++p) {
        int e = csr[p];
        float w = wb[e];
        den += w;
        acc8(a, *(const uint4*)(eebb + ((long)esrc[e] << 9) + lane * 8), w);
    }
    float g = tanhf(ga[0]);
    float inv = den > 0.0f ? g / den : 0.0f;
    const float* tr = t_all + ((long)ng << 9) + lane * 8;
    float4 t0 = *(const float4*)tr;
    float4 t1 = *(const float4*)(tr + 4);
    float o[8];
    o[0] = t0.x + inv * a[0]; o[1] = t0.y + inv * a[1];
    o[2] = t0.z + inv * a[2]; o[3] = t0.w + inv * a[3];
    o[4] = t1.x + inv * a[4]; o[5] = t1.y + inv * a[5];
    o[6] = t1.z + inv * a[6]; o[7] = t1.w + inv * a[7];
    float* op = out + ((long)ng << 9) + lane * 8;
    *(float4*)op = make_float4(o[0], o[1], o[2], o[3]);
    *(float4*)(op + 4) = make_float4(o[4], o[5], o[6], o[7]);
    *(uint4*)(nb + ((long)ng << 9) + lane * 8) = pack8(o);
}

// ---------------- bf16 MFMA GEMM 128x128 (m97 structure), two epilogues ----------------
// MODE 0: Cb(bf16) = A@Bt^T + bias.   MODE 1: Cf(f32) += tanh(gs[0]) * (A@Bt^T + bias)
template<int MODE>
__global__ __launch_bounds__(256) void gemm_bt128(
    const unsigned short* __restrict__ A, const unsigned short* __restrict__ Bt,
    const float* __restrict__ bias, unsigned short* __restrict__ Cb,
    float* __restrict__ Cf, const float* __restrict__ gs, int N, int K)
{
    __shared__ short As[128 * 32];
    __shared__ short Bs[128 * 32];
    int tid = threadIdx.x;
    int lane = tid & 63;
    int w = tid >> 6;
    int wm = w >> 1, wn = w & 1;
    int bm = blockIdx.x * 128, bn = blockIdx.y * 128;

    f32x4 acc[4][4] = {};

    int srow = tid >> 2;
    int scol = (tid & 3) * 8;
    const unsigned short* Ag0 = A + (long)(bm + srow) * K + scol;
    const unsigned short* Ag1 = A + (long)(bm + 64 + srow) * K + scol;
    const unsigned short* Bg0 = Bt + (long)(bn + srow) * K + scol;
    const unsigned short* Bg1 = Bt + (long)(bn + 64 + srow) * K + scol;

    int ar = wm * 64 + (lane & 15);
    int br = wn * 64 + (lane & 15);
    int kq = (lane >> 4) * 8;

    for (int k0 = 0; k0 < K; k0 += 32) {
        __builtin_amdgcn_global_load_lds(
            (const __attribute__((address_space(1))) unsigned int*)(Ag0 + k0),
            (__attribute__((address_space(3))) unsigned int*)(As + tid * 8), 16, 0, 0);
        __builtin_amdgcn_global_load_lds(
            (const __attribute__((address_space(1))) unsigned int*)(Ag1 + k0),
            (__attribute__((address_space(3))) unsigned int*)(As + 2048 + tid * 8), 16, 0, 0);
        __builtin_amdgcn_global_load_lds(
            (const __attribute__((address_space(1))) unsigned int*)(Bg0 + k0),
            (__attribute__((address_space(3))) unsigned int*)(Bs + tid * 8), 16, 0, 0);
        __builtin_amdgcn_global_load_lds(
            (const __attribute__((address_space(1))) unsigned int*)(Bg1 + k0),
            (__attribute__((address_space(3))) unsigned int*)(Bs + 2048 + tid * 8), 16, 0, 0);
        __syncthreads();

        bf16x8 af[4], bf[4];
#pragma unroll
        for (int rb = 0; rb < 4; ++rb)
            af[rb] = *(const bf16x8*)&As[(ar + rb * 16) * 32 + kq];
#pragma unroll
        for (int cb = 0; cb < 4; ++cb)
            bf[cb] = *(const bf16x8*)&Bs[(br + cb * 16) * 32 + kq];
#pragma unroll
        for (int rb = 0; rb < 4; ++rb)
#pragma unroll
            for (int cb = 0; cb < 4; ++cb)
                acc[rb][cb] = __builtin_amdgcn_mfma_f32_16x16x32_bf16(
                    af[rb], bf[cb], acc[rb][cb], 0, 0, 0);
        __syncthreads();
    }

    float g = (MODE == 1) ? tanhf(gs[0]) : 0.0f;
#pragma unroll
    for (int rb = 0; rb < 4; ++rb) {
        int row0 = bm + wm * 64 + rb * 16 + ((lane >> 4) << 2);
#pragma unroll
        for (int cb = 0; cb < 4; ++cb) {
            int col = bn + wn * 64 + cb * 16 + (lane & 15);
            float bv = bias[col];
#pragma unroll
            for (int r = 0; r < 4; ++r) {
                long idx = (long)(row0 + r) * N + col;
                if (MODE == 0) Cb[idx] = f2bf(acc[rb][cb][r] + bv);
                else           Cf[idx] += g * (acc[rb][cb][r] + bv);
            }
        }
    }
}

// ---------------- bf16 MFMA skinny GEMM: Cb[M,64] = A[M,512] @ Bt[64,512]^T + bias ----------------
__global__ __launch_bounds__(256) void gemm_bt_n64(
    const unsigned short* __restrict__ A, const unsigned short* __restrict__ Bt,
    const float* __restrict__ bias, unsigned short* __restrict__ Cb)
{
    __shared__ short As[128 * 32];
    __shared__ short Bs[64 * 32];
    int tid = threadIdx.x;
    int lane = tid & 63;
    int w = tid >> 6;
    int bm = blockIdx.x * 128;

    f32x4 acc[2][4] = {};

    int srow = tid >> 2;
    int scol = (tid & 3) * 8;
    const unsigned short* Ag0 = A + (long)(bm + srow) * DD + scol;
    const unsigned short* Ag1 = A + (long)(bm + 64 + srow) * DD + scol;
    const unsigned short* Bg = Bt + (long)srow * DD + scol;

    int ar = w * 32 + (lane & 15);
    int br = (lane & 15);
    int kq = (lane >> 4) * 8;

    for (int k0 = 0; k0 < DD; k0 += 32) {
        __builtin_amdgcn_global_load_lds(
            (const __attribute__((address_space(1))) unsigned int*)(Ag0 + k0),
            (__attribute__((address_space(3))) unsigned int*)(As + tid * 8), 16, 0, 0);
        __builtin_amdgcn_global_load_lds(
            (const __attribute__((address_space(1))) unsigned int*)(Ag1 + k0),
            (__attribute__((address_space(3))) unsigned int*)(As + 2048 + tid * 8), 16, 0, 0);
        __builtin_amdgcn_global_load_lds(
            (const __attribute__((address_space(1))) unsigned int*)(Bg + k0),
            (__attribute__((address_space(3))) unsigned int*)(Bs + tid * 8), 16, 0, 0);
        __syncthreads();

        bf16x8 af[2], bf[4];
#pragma unroll
        for (int rb = 0; rb < 2; ++rb)
            af[rb] = *(const bf16x8*)&As[(ar + rb * 16) * 32 + kq];
#pragma unroll
        for (int cb = 0; cb < 4; ++cb)
            bf[cb] = *(const bf16x8*)&Bs[(br + cb * 16) * 32 + kq];
#pragma unroll
        for (int rb = 0; rb < 2; ++rb)
#pragma unroll
            for (int cb = 0; cb < 4; ++cb)
                acc[rb][cb] = __builtin_amdgcn_mfma_f32_16x16x32_bf16(
                    af[rb], bf[cb], acc[rb][cb], 0, 0, 0);
        __syncthreads();
    }

#pragma unroll
    for (int rb = 0; rb < 2; ++rb) {
        int row0 = bm + w * 32 + rb * 16 + ((lane >> 4) << 2);
#pragma unroll
        for (int cb = 0; cb < 4; ++cb) {
            int col = cb * 16 + (lane & 15);
            float bv = bias[col];
#pragma unroll
            for (int r = 0; r < 4; ++r)
                Cb[(long)(row0 + r) * DKK + col] = f2bf(acc[rb][cb][r] + bv);
        }
    }
}

// ---------------- fp32 tiled GEMM (one-time Wgk = Wgnn @ Wk) ----------------
__global__ void gemm_tiled(const float* __restrict__ A, const float* __restrict__ Bw,
                           float* __restrict__ C, int K, int Nc) {
    __shared__ float As[16][64];
    __shared__ float Bs[16][64];
    int tid = threadIdx.x;
    int tx = tid & 15, ty = tid >> 4;
    int bm = blockIdx.x * 64, bn = blockIdx.y * 64;
    float acc[4][4] = {};
    int arow = bm + (tid >> 2);
    long aoff = (long)arow * K;
    int kk0 = (tid & 3) * 4;
    int arowl = tid >> 2;
    for (int k0 = 0; k0 < K; k0 += 16) {
        float4 av = *(const float4*)(A + aoff + k0 + kk0);
        As[kk0 + 0][arowl] = av.x;
        As[kk0 + 1][arowl] = av.y;
        As[kk0 + 2][arowl] = av.z;
        As[kk0 + 3][arowl] = av.w;
        float4 bv = *(const float4*)(Bw + (long)(k0 + (tid >> 4)) * Nc + bn + (tid & 15) * 4);
        *(float4*)&Bs[tid >> 4][(tid & 15) * 4] = bv;
        __syncthreads();
#pragma unroll
        for (int k = 0; k < 16; ++k) {
            float4 a = *(const float4*)&As[k][ty * 4];
            float4 b = *(const float4*)&Bs[k][tx * 4];
            acc[0][0] += a.x * b.x; acc[0][1] += a.x * b.y; acc[0][2] += a.x * b.z; acc[0][3] += a.x * b.w;
            acc[1][0] += a.y * b.x; acc[1][1] += a.y * b.y; acc[1][2] += a.y * b.z; acc[1][3] += a.y * b.w;
            acc[2][0] += a.z * b.x; acc[2][1] += a.z * b.y; acc[2][2] += a.z * b.z; acc[2][3] += a.z * b.w;
            acc[3][0] += a.w * b.x; acc[3][1] += a.w * b.y; acc[3][2] += a.w * b.z; acc[3][3] += a.w * b.w;
        }
        __syncthreads();
    }
#pragma unroll
    for (int i = 0; i < 4; ++i)
        *(float4*)(C + (long)(bm + ty * 4 + i) * Nc + bn + tx * 4) =
            make_float4(acc[i][0], acc[i][1], acc[i][2], acc[i][3]);
}

// ---------------- attention dots (batched, bf16 k/q) ----------------
__global__ void k_dots(const unsigned short* __restrict__ kb, const unsigned short* __restrict__ qb,
                       const int* __restrict__ es_all, const int* __restrict__ ed_all,
                       float* __restrict__ wbuf) {
    int eg = (blockIdx.x * 256 + threadIdx.x) >> 6;   // [0, B*EA)
    int lane = threadIdx.x & 63;
    int b = eg >> 16;
    int s = es_all[eg], dd = ed_all[eg];
    float p = bf2f(qb[((long)(b * NT + dd) << 6) + lane]) * bf2f(kb[((long)(b * ME + s) << 6) + lane]);
#pragma unroll
    for (int off = 32; off > 0; off >>= 1) p += __shfl_down(p, off);
    if (lane == 0) wbuf[eg] = expf(p * 0.125f);  // softmax max-shift is exact no-op
}

extern "C" void kernel_launch(void* const* d_in, const int* in_sizes, int n_in,
                              void* d_out, int out_size, void* d_ws, size_t ws_size,
                              hipStream_t stream) {
    const float* t_all   = (const float*)d_in[0];
    const int*   t2e_all = (const int*)d_in[1];
    const int*   ei_all  = (const int*)d_in[2];
    const int*   es_all  = (const int*)d_in[3];
    const int*   ed_all  = (const int*)d_in[4];
    const float* Wgnn    = (const float*)d_in[5];
    const float* bgnn    = (const float*)d_in[6];
    const float* Wk      = (const float*)d_in[7];
    const float* bk      = (const float*)d_in[8];
    const float* Wq      = (const float*)d_in[9];
    const float* bq      = (const float*)d_in[10];
    const float* Wl      = (const float*)d_in[11];
    const float* bl      = (const float*)d_in[12];
    const float* ga      = (const float*)d_in[13];
    const float* gb      = (const float*)d_in[14];
    float* out = (float*)d_out;

    // batched workspace (~184 MB of the 256 MiB budget)
    char* wsb = (char*)d_ws;
    size_t off = 0;
    unsigned short* zb    = (unsigned short*)(wsb + off); off += (size_t)BB * ME * DD * 2;  // 67.1 MB
    unsigned short* eeb   = (unsigned short*)(wsb + off); off += (size_t)BB * ME * DD * 2;  // 67.1 MB
    unsigned short* tb    = (unsigned short*)(wsb + off); off += (size_t)BB * NT * DD * 2;  // 16.8 MB
    unsigned short* nb    = (unsigned short*)(wsb + off); off += (size_t)BB * NT * DD * 2;  // 16.8 MB
    unsigned short* kmatb = (unsigned short*)(wsb + off); off += (size_t)BB * ME * DKK * 2; // 8.4 MB
    unsigned short* qmatb = (unsigned short*)(wsb + off); off += (size_t)BB * NT * DKK * 2; // 2.1 MB
    unsigned short* Wgt   = (unsigned short*)(wsb + off); off += (size_t)DD * DD * 2;
    unsigned short* Wlt   = (unsigned short*)(wsb + off); off += (size_t)DD * DD * 2;
    unsigned short* Wqt   = (unsigned short*)(wsb + off); off += (size_t)DKK * DD * 2;
    unsigned short* Wgkt  = (unsigned short*)(wsb + off); off += (size_t)DKK * DD * 2;
    float* Wgk  = (float*)(wsb + off); off += (size_t)DD * DKK * 4;
    float* bgk  = (float*)(wsb + off); off += 64 * 4;
    float* dinv = (float*)(wsb + off); off += (size_t)BB * ME * 4;
    float* wbuf = (float*)(wsb + off); off += (size_t)BB * EA * 4;
    int* cntG  = (int*)(wsb + off); off += (size_t)BB * ME * 4;   // cntG+cntA contiguous
    int* cntA  = (int*)(wsb + off); off += (size_t)BB * NT * 4;
    int* offsG = (int*)(wsb + off); off += (size_t)BB * (ME + 1) * 4;
    int* curG  = (int*)(wsb + off); off += (size_t)BB * ME * 4;
    int* csrG  = (int*)(wsb + off); off += (size_t)BB * EG * 4;
    int* offsA = (int*)(wsb + off); off += (size_t)BB * (NT + 1) * 4;
    int* curA  = (int*)(wsb + off); off += (size_t)BB * NT * 4;
    int* csrA  = (int*)(wsb + off); off += (size_t)BB * EA * 4;

    // ---- one-time weight prep ----
    gemm_tiled<<<dim3(DD / 64, 1), 256, 0, stream>>>(Wgnn, Wk, Wgk, DD, DKK);  // Wgk = Wgnn@Wk
    k_wt2<<<dim3((DD * DD) / 256, 2), 256, 0, stream>>>(Wgnn, Wgt, Wl, Wlt);
    k_wt64<<<(DKK * DD) / 256, 256, 0, stream>>>(Wq, Wqt);
    k_wt64<<<(DKK * DD) / 256, 256, 0, stream>>>(Wgk, Wgkt);
    k_bgk<<<1, 64, 0, stream>>>(bgnn, Wk, bk, bgk);

    // ---- batched CSR build ----
    hipMemsetAsync(cntG, 0, (size_t)BB * (ME + NT) * 4, stream);
    k_hist2<<<(BB * (EG + EA)) / 256, 256, 0, stream>>>(ei_all, ed_all, cntG, cntA);
    k_scan2<<<2 * BB, 1024, 0, stream>>>(cntG, offsG, curG, dinv, cntA, offsA, curA);
    k_fill2<<<(BB * (EG + EA)) / 256, 256, 0, stream>>>(ei_all, ed_all, curG, csrG, curA, csrA);

    // ---- bf16 tokens ----
    k_cast<<<(int)(((long)BB * NT * DD / 4) / 256), 256, 0, stream>>>(t_all, tb);

    // ---- GCN aggregate -> zb, then eeb = bf16(zb @ Wgnn + bgnn)  [M = B*ME] ----
    k_gcn_gather<<<(BB * ME * 64) / 256, 256, 0, stream>>>(tb, t2e_all, dinv, offsG, csrG, ei_all, zb);
    gemm_bt128<0><<<dim3((BB * ME) / 128, DD / 128), 256, 0, stream>>>(
        zb, Wgt, bgnn, eeb, nullptr, nullptr, DD, DD);

    // ---- k = zb @ (Wgnn·Wk) + (bgnn·Wk + bk);  q = tb @ Wq + bq ----
    gemm_bt_n64<<<(BB * ME) / 128, 256, 0, stream>>>(zb, Wgkt, bgk, kmatb);
    gemm_bt_n64<<<(BB * NT) / 128, 256, 0, stream>>>(tb, Wqt, bq, qmatb);

    // ---- attention ----
    k_dots<<<(BB * EA * 64) / 256, 256, 0, stream>>>(kmatb, qmatb, es_all, ed_all, wbuf);
    k_att_gather<<<(BB * NT * 64) / 256, 256, 0, stream>>>(
        eeb, wbuf, offsA, csrA, es_all, t_all, ga, out, nb);

    // ---- final: out += tanh(gb) * (nb @ Wl + bl)  [M = B*NT] ----
    gemm_bt128<1><<<dim3((BB * NT) / 128, DD / 128), 256, 0, stream>>>(
        nb, Wlt, bl, nullptr, out, gb, DD, DD);
}

// Round 7
// 458.208 us; speedup vs baseline: 4.8419x; 1.1767x over previous
//
#include <hip/hip_runtime.h>
#include <math.h>

// B=4, N=4096, M=16384, Eg=65536, Ea=65536, D=512, DK=64
#define BB 4
#define NT 4096
#define ME 16384
#define EG 65536
#define EA 65536
#define DD 512
#define DKK 64

using bf16x8 = __attribute__((ext_vector_type(8))) short;
using f32x4  = __attribute__((ext_vector_type(4))) float;

static __device__ __forceinline__ unsigned short f2bf(float f) {
    unsigned u = __float_as_uint(f);
    u += 0x7fffu + ((u >> 16) & 1u);
    return (unsigned short)(u >> 16);
}
static __device__ __forceinline__ void acc8(float* a, uint4 v, float s) {
    a[0] += s * __uint_as_float(v.x << 16);
    a[1] += s * __uint_as_float(v.x & 0xffff0000u);
    a[2] += s * __uint_as_float(v.y << 16);
    a[3] += s * __uint_as_float(v.y & 0xffff0000u);
    a[4] += s * __uint_as_float(v.z << 16);
    a[5] += s * __uint_as_float(v.z & 0xffff0000u);
    a[6] += s * __uint_as_float(v.w << 16);
    a[7] += s * __uint_as_float(v.w & 0xffff0000u);
}
static __device__ __forceinline__ uint4 pack8(const float* a) {
    uint4 o;
    o.x = (unsigned)f2bf(a[0]) | ((unsigned)f2bf(a[1]) << 16);
    o.y = (unsigned)f2bf(a[2]) | ((unsigned)f2bf(a[3]) << 16);
    o.z = (unsigned)f2bf(a[4]) | ((unsigned)f2bf(a[5]) << 16);
    o.w = (unsigned)f2bf(a[6]) | ((unsigned)f2bf(a[7]) << 16);
    return o;
}

// ---------------- batched CSR build ----------------
__global__ void k_hist2(const int* __restrict__ ei_all, const int* __restrict__ ed_all,
                        int* __restrict__ cntG, int* __restrict__ cntA) {
    int i = blockIdx.x * 256 + threadIdx.x;
    if (i < BB * EG) {
        int b = i >> 16, e = i & (EG - 1);
        int dst = ei_all[(size_t)b * 2 * EG + EG + e];
        atomicAdd(&cntG[b * ME + dst], 1);
    } else {
        int j = i - BB * EG;
        atomicAdd(&cntA[(j >> 16) * NT + ed_all[j]], 1);
    }
}

// blocks 0..3: graph scan (ME keys, +dinv); blocks 4..7: attention scan (NT keys)
__global__ __launch_bounds__(1024) void k_scan2(
    const int* __restrict__ cntG, int* __restrict__ offsG, int* __restrict__ curG,
    float* __restrict__ dinv,
    const int* __restrict__ cntA, int* __restrict__ offsA, int* __restrict__ curA) {
    __shared__ int sums[1024];
    int tid = threadIdx.x;
    int bid = blockIdx.x;
    const int* cnt;
    int *offs, *cur;
    float* dv = nullptr;
    int C, nk;
    if (bid < BB) {
        cnt = cntG + bid * ME; offs = offsG + bid * (ME + 1); cur = curG + bid * ME;
        dv = dinv + bid * ME; C = ME / 1024; nk = ME;
    } else {
        int b = bid - BB;
        cnt = cntA + b * NT; offs = offsA + b * (NT + 1); cur = curA + b * NT;
        C = NT / 1024; nk = NT;
    }
    int local[16];
    int tot = 0;
    for (int i = 0; i < C; ++i) { local[i] = cnt[tid * C + i]; tot += local[i]; }
    sums[tid] = tot;
    __syncthreads();
    for (int d = 1; d < 1024; d <<= 1) {
        int v = (tid >= d) ? sums[tid - d] : 0;
        __syncthreads();
        sums[tid] += v;
        __syncthreads();
    }
    int run = sums[tid] - tot;
    for (int i = 0; i < C; ++i) {
        int idx = tid * C + i;
        offs[idx] = run;
        cur[idx] = run;
        if (dv) dv[idx] = rsqrtf((float)local[i] + 1.0f);  // +1 self loop
        run += local[i];
    }
    if (tid == 1023) offs[nk] = run;
}

// CSR-direct fill: graph slots hold (token_row, dinv-bits); attention slots hold (src, dst)
__global__ void k_fill2(const int* __restrict__ ei_all, const int* __restrict__ es_all,
                        const int* __restrict__ ed_all, const int* __restrict__ t2e_all,
                        const float* __restrict__ dinv,
                        int* __restrict__ curG, int2* __restrict__ csrG,
                        int* __restrict__ curA, int2* __restrict__ csrA) {
    int i = blockIdx.x * 256 + threadIdx.x;
    if (i < BB * EG) {
        int b = i >> 16, e = i & (EG - 1);
        const int* ei = ei_all + (size_t)b * 2 * EG;
        int s = ei[e], d = ei[EG + e];
        int p = atomicAdd(&curG[b * ME + d], 1);
        int2 v;
        v.x = t2e_all[(b << 14) + s];
        v.y = __float_as_int(dinv[b * ME + s]);
        csrG[(size_t)b * EG + p] = v;
    } else {
        int j = i - BB * EG;
        int b = j >> 16;
        int p = atomicAdd(&curA[b * NT + ed_all[j]], 1);
        int2 v;
        v.x = es_all[j];
        v.y = ed_all[j];
        csrA[(size_t)b * EA + p] = v;
    }
}

// ---------------- casts / weight prep ----------------
__global__ void k_cast(const float* __restrict__ x, unsigned short* __restrict__ xb) {
    long i = (long)blockIdx.x * blockDim.x + threadIdx.x;
    float4 v = *(const float4*)(x + (i << 2));
    ushort4 o;
    o.x = f2bf(v.x); o.y = f2bf(v.y); o.z = f2bf(v.z); o.w = f2bf(v.w);
    *(ushort4*)(xb + (i << 2)) = o;
}

// Wlt[n][k] = bf16(Wl[k][n])  (512x512)
__global__ void k_wt(const float* __restrict__ W, unsigned short* __restrict__ Wt) {
    int i = blockIdx.x * 256 + threadIdx.x;
    int n = i >> 9, k = i & 511;
    Wt[i] = f2bf(W[((long)k << 9) + n]);
}
// Wqt[n][k] = bf16(Wq[k][n])  ([512x64] -> [64,512])
__global__ void k_wt64(const float* __restrict__ W, unsigned short* __restrict__ Wt) {
    int i = blockIdx.x * 256 + threadIdx.x;
    int n = i >> 9, k = i & 511;
    Wt[i] = f2bf(W[k * 64 + n]);
}
// BtC[576][512]: rows 0..511 = Wgnn^T; rows 512..575 = Wgk^T
__global__ void k_wtC(const float* __restrict__ Wgnn, const float* __restrict__ Wgk,
                      unsigned short* __restrict__ BtC) {
    int i = blockIdx.x * 256 + threadIdx.x;  // 576*512
    int n = i >> 9, k = i & 511;
    BtC[i] = f2bf(n < 512 ? Wgnn[((long)k << 9) + n] : Wgk[k * 64 + (n - 512)]);
}
// biasC[576]: [bgnn ; bgk] with bgk[n] = bk[n] + sum_k bgnn[k]*Wk[k][n]
__global__ void k_biasC(const float* __restrict__ bgnn, const float* __restrict__ Wk,
                        const float* __restrict__ bk, float* __restrict__ biasC) {
    int tid = threadIdx.x;  // 576
    if (tid < 512) { biasC[tid] = bgnn[tid]; return; }
    int n = tid - 512;
    float s = bk[n];
    for (int k = 0; k < DD; ++k) s += bgnn[k] * Wk[k * 64 + n];
    biasC[tid] = s;
}

// ---------------- GCN aggregation: one wave per (b,m), CSR-direct ----------------
__global__ __launch_bounds__(256) void k_gcn_gather(
    const unsigned short* __restrict__ tb, const int* __restrict__ t2e_all,
    const float* __restrict__ dinv, const int* __restrict__ offsG,
    const int2* __restrict__ csrG, unsigned short* __restrict__ zb)
{
    int mg = (blockIdx.x * 256 + threadIdx.x) >> 6;   // [0, B*ME)
    int lane = threadIdx.x & 63;
    int b = mg >> 14;
    int m = mg & (ME - 1);
    const int* offs = offsG + b * (ME + 1);
    const int2* csr = csrG + (size_t)b * EG;
    long tbase = (long)b * NT;

    float dm = dinv[mg];
    float a[8] = {0, 0, 0, 0, 0, 0, 0, 0};
    acc8(a, *(const uint4*)(tb + ((tbase + t2e_all[mg]) << 9) + lane * 8), dm);
    int beg = offs[m], end = offs[m + 1];
    for (int p = beg; p < end; ++p) {
        int2 rw = csr[p];                 // (token row, dinv bits) — contiguous 8B
        acc8(a, *(const uint4*)(tb + ((tbase + rw.x) << 9) + lane * 8), __int_as_float(rw.y));
    }
#pragma unroll
    for (int j = 0; j < 8; ++j) a[j] *= dm;
    *(uint4*)(zb + ((long)mg << 9) + lane * 8) = pack8(a);
}

// ---------------- attention dots: one thread per CSR position ----------------
__global__ void k_dots(const unsigned short* __restrict__ kmatb,
                       const unsigned short* __restrict__ qmatb,
                       const int2* __restrict__ csrA, float* __restrict__ wbuf) {
    int p = blockIdx.x * 256 + threadIdx.x;   // [0, B*EA)
    int b = p >> 16;
    int2 sd = csrA[p];
    const uint4* kr = (const uint4*)(kmatb + ((long)(b * ME + sd.x) << 6));
    const uint4* qr = (const uint4*)(qmatb + ((long)(b * NT + sd.y) << 6));
    float dot = 0.0f;
#pragma unroll
    for (int j = 0; j < 8; ++j) {
        uint4 kv = kr[j];
        uint4 qv = qr[j];
        dot += __uint_as_float(kv.x << 16) * __uint_as_float(qv.x << 16)
             + __uint_as_float(kv.x & 0xffff0000u) * __uint_as_float(qv.x & 0xffff0000u)
             + __uint_as_float(kv.y << 16) * __uint_as_float(qv.y << 16)
             + __uint_as_float(kv.y & 0xffff0000u) * __uint_as_float(qv.y & 0xffff0000u)
             + __uint_as_float(kv.z << 16) * __uint_as_float(qv.z << 16)
             + __uint_as_float(kv.z & 0xffff0000u) * __uint_as_float(qv.z & 0xffff0000u)
             + __uint_as_float(kv.w << 16) * __uint_as_float(qv.w << 16)
             + __uint_as_float(kv.w & 0xffff0000u) * __uint_as_float(qv.w & 0xffff0000u);
    }
    wbuf[p] = expf(dot * 0.125f);  // /sqrt(64); softmax max-shift is exact no-op
}

// ---------------- attention aggregation: one wave per (b,n), CSR-order ----------------
__global__ __launch_bounds__(256) void k_att_gather(
    const unsigned short* __restrict__ eeb, const float* __restrict__ wbuf,
    const int* __restrict__ offsA, const int2* __restrict__ csrA,
    const float* __restrict__ t_all, const float* __restrict__ ga,
    float* __restrict__ out, unsigned short* __restrict__ nb)
{
    int ng = (blockIdx.x * 256 + threadIdx.x) >> 6;   // [0, B*NT)
    int lane = threadIdx.x & 63;
    int b = ng >> 12;
    int n = ng & (NT - 1);
    const int* offs = offsA + b * (NT + 1);
    const int2* csr = csrA + (size_t)b * EA;
    const float* wb = wbuf + (size_t)b * EA;
    const unsigned short* eebb = eeb + ((size_t)b * ME << 9);

    float a[8] = {0, 0, 0, 0, 0, 0, 0, 0};
    float den = 0.0f;
    int beg = offs[n], end = offs[n + 1];
    for (int p = beg; p < end; ++p) {
        int s = csr[p].x;            // contiguous
        float w = wb[p];             // contiguous (CSR order)
        den += w;
        acc8(a, *(const uint4*)(eebb + ((long)s << 9) + lane * 8), w);
    }
    float g = tanhf(ga[0]);
    float inv = den > 0.0f ? g / den : 0.0f;
    const float* tr = t_all + ((long)ng << 9) + lane * 8;
    float4 t0 = *(const float4*)tr;
    float4 t1 = *(const float4*)(tr + 4);
    float o[8];
    o[0] = t0.x + inv * a[0]; o[1] = t0.y + inv * a[1];
    o[2] = t0.z + inv * a[2]; o[3] = t0.w + inv * a[3];
    o[4] = t1.x + inv * a[4]; o[5] = t1.y + inv * a[5];
    o[6] = t1.z + inv * a[6]; o[7] = t1.w + inv * a[7];
    float* op = out + ((long)ng << 9) + lane * 8;
    *(float4*)op = make_float4(o[0], o[1], o[2], o[3]);
    *(float4*)(op + 4) = make_float4(o[4], o[5], o[6], o[7]);
    *(uint4*)(nb + ((long)ng << 9) + lane * 8) = pack8(o);
}

// ---------------- wide-N bf16 MFMA GEMM: 64-row tile x full N, A staged once ----------------
// CB = col-tiles per wave (16 cols each); total N = CB*64.
// MODE 0 (CB=9): cols<512 -> Cb=eeb bf16; cols>=512 -> Ck=kmatb bf16 (fused k-proj)
// MODE 1 (CB=8): Cf += tanh(gs[0]) * (acc + bias)
template<int CB, int MODE>
__global__ __launch_bounds__(256, 2) void gemm_wide(
    const unsigned short* __restrict__ A,   // [M,512]
    const unsigned short* __restrict__ Bt,  // [CB*64, 512]
    const float* __restrict__ bias,         // [CB*64]
    unsigned short* __restrict__ Cb, unsigned short* __restrict__ Ck,
    float* __restrict__ Cf, const float* __restrict__ gs)
{
    __shared__ short As[64 * 32];
    __shared__ short Bs[CB * 64 * 32];
    int tid = threadIdx.x;
    int lane = tid & 63;
    int w = tid >> 6;
    long bm = (long)blockIdx.x * 64;

    f32x4 acc[4][CB] = {};

    int srow = tid >> 2;
    int scol = (tid & 3) * 8;
    const unsigned short* Ag = A + (bm + srow) * DD + scol;
    const unsigned short* Bg = Bt + (long)srow * DD + scol;

    int ar = lane & 15;
    int kq = (lane >> 4) * 8;

    for (int k0 = 0; k0 < DD; k0 += 32) {
        __builtin_amdgcn_global_load_lds(
            (const __attribute__((address_space(1))) unsigned int*)(Ag + k0),
            (__attribute__((address_space(3))) unsigned int*)(As + tid * 8), 16, 0, 0);
#pragma unroll
        for (int c = 0; c < CB; ++c)
            __builtin_amdgcn_global_load_lds(
                (const __attribute__((address_space(1))) unsigned int*)(Bg + (long)c * 64 * DD + k0),
                (__attribute__((address_space(3))) unsigned int*)(Bs + c * 2048 + tid * 8), 16, 0, 0);
        __syncthreads();

        bf16x8 af[4];
#pragma unroll
        for (int rb = 0; rb < 4; ++rb)
            af[rb] = *(const bf16x8*)&As[(ar + rb * 16) * 32 + kq];
#pragma unroll
        for (int cb = 0; cb < CB; ++cb) {
            bf16x8 bf = *(const bf16x8*)&Bs[(w * (CB * 16) + cb * 16 + ar) * 32 + kq];
#pragma unroll
            for (int rb = 0; rb < 4; ++rb)
                acc[rb][cb] = __builtin_amdgcn_mfma_f32_16x16x32_bf16(af[rb], bf, acc[rb][cb], 0, 0, 0);
        }
        __syncthreads();
    }

    float g = (MODE == 1) ? tanhf(gs[0]) : 0.0f;
#pragma unroll
    for (int rb = 0; rb < 4; ++rb) {
        long row0 = bm + rb * 16 + ((lane >> 4) << 2);
#pragma unroll
        for (int cb = 0; cb < CB; ++cb) {
            int col = w * (CB * 16) + cb * 16 + (lane & 15);
            float bv = bias[col];
            if (MODE == 0) {
                if (col < 512) {
#pragma unroll
                    for (int r = 0; r < 4; ++r)
                        Cb[(row0 + r) * DD + col] = f2bf(acc[rb][cb][r] + bv);
                } else {
#pragma unroll
                    for (int r = 0; r < 4; ++r)
                        Ck[(row0 + r) * DKK + (col - 512)] = f2bf(acc[rb][cb][r] + bv);
                }
            } else {
#pragma unroll
                for (int r = 0; r < 4; ++r)
                    Cf[(row0 + r) * DD + col] += g * (acc[rb][cb][r] + bv);
            }
        }
    }
}

// ---------------- bf16 MFMA skinny GEMM (q-proj): Cb[M,64] = A[M,512]@Bt[64,512]^T + bias ----------------
__global__ __launch_bounds__(256) void gemm_bt_n64(
    const unsigned short* __restrict__ A, const unsigned short* __restrict__ Bt,
    const float* __restrict__ bias, unsigned short* __restrict__ Cb)
{
    __shared__ short As[128 * 32];
    __shared__ short Bs[64 * 32];
    int tid = threadIdx.x;
    int lane = tid & 63;
    int w = tid >> 6;
    int bm = blockIdx.x * 128;

    f32x4 acc[2][4] = {};

    int srow = tid >> 2;
    int scol = (tid & 3) * 8;
    const unsigned short* Ag0 = A + (long)(bm + srow) * DD + scol;
    const unsigned short* Ag1 = A + (long)(bm + 64 + srow) * DD + scol;
    const unsigned short* Bg = Bt + (long)srow * DD + scol;

    int ar = w * 32 + (lane & 15);
    int br = (lane & 15);
    int kq = (lane >> 4) * 8;

    for (int k0 = 0; k0 < DD; k0 += 32) {
        __builtin_amdgcn_global_load_lds(
            (const __attribute__((address_space(1))) unsigned int*)(Ag0 + k0),
            (__attribute__((address_space(3))) unsigned int*)(As + tid * 8), 16, 0, 0);
        __builtin_amdgcn_global_load_lds(
            (const __attribute__((address_space(1))) unsigned int*)(Ag1 + k0),
            (__attribute__((address_space(3))) unsigned int*)(As + 2048 + tid * 8), 16, 0, 0);
        __builtin_amdgcn_global_load_lds(
            (const __attribute__((address_space(1))) unsigned int*)(Bg + k0),
            (__attribute__((address_space(3))) unsigned int*)(Bs + tid * 8), 16, 0, 0);
        __syncthreads();

        bf16x8 af[2], bf[4];
#pragma unroll
        for (int rb = 0; rb < 2; ++rb)
            af[rb] = *(const bf16x8*)&As[(ar + rb * 16) * 32 + kq];
#pragma unroll
        for (int cb = 0; cb < 4; ++cb)
            bf[cb] = *(const bf16x8*)&Bs[(br + cb * 16) * 32 + kq];
#pragma unroll
        for (int rb = 0; rb < 2; ++rb)
#pragma unroll
            for (int cb = 0; cb < 4; ++cb)
                acc[rb][cb] = __builtin_amdgcn_mfma_f32_16x16x32_bf16(
                    af[rb], bf[cb], acc[rb][cb], 0, 0, 0);
        __syncthreads();
    }

#pragma unroll
    for (int rb = 0; rb < 2; ++rb) {
        int row0 = bm + w * 32 + rb * 16 + ((lane >> 4) << 2);
#pragma unroll
        for (int cb = 0; cb < 4; ++cb) {
            int col = cb * 16 + (lane & 15);
            float bv = bias[col];
#pragma unroll
            for (int r = 0; r < 4; ++r)
                Cb[(long)(row0 + r) * DKK + col] = f2bf(acc[rb][cb][r] + bv);
        }
    }
}

// ---------------- fp32 tiled GEMM (one-time Wgk = Wgnn @ Wk) ----------------
__global__ void gemm_tiled(const float* __restrict__ A, const float* __restrict__ Bw,
                           float* __restrict__ C, int K, int Nc) {
    __shared__ float As[16][64];
    __shared__ float Bs[16][64];
    int tid = threadIdx.x;
    int tx = tid & 15, ty = tid >> 4;
    int bm = blockIdx.x * 64, bn = blockIdx.y * 64;
    float acc[4][4] = {};
    int arow = bm + (tid >> 2);
    long aoff = (long)arow * K;
    int kk0 = (tid & 3) * 4;
    int arowl = tid >> 2;
    for (int k0 = 0; k0 < K; k0 += 16) {
        float4 av = *(const float4*)(A + aoff + k0 + kk0);
        As[kk0 + 0][arowl] = av.x;
        As[kk0 + 1][arowl] = av.y;
        As[kk0 + 2][arowl] = av.z;
        As[kk0 + 3][arowl] = av.w;
        float4 bv = *(const float4*)(Bw + (long)(k0 + (tid >> 4)) * Nc + bn + (tid & 15) * 4);
        *(float4*)&Bs[tid >> 4][(tid & 15) * 4] = bv;
        __syncthreads();
#pragma unroll
        for (int k = 0; k < 16; ++k) {
            float4 a = *(const float4*)&As[k][ty * 4];
            float4 b = *(const float4*)&Bs[k][tx * 4];
            acc[0][0] += a.x * b.x; acc[0][1] += a.x * b.y; acc[0][2] += a.x * b.z; acc[0][3] += a.x * b.w;
            acc[1][0] += a.y * b.x; acc[1][1] += a.y * b.y; acc[1][2] += a.y * b.z; acc[1][3] += a.y * b.w;
            acc[2][0] += a.z * b.x; acc[2][1] += a.z * b.y; acc[2][2] += a.z * b.z; acc[2][3] += a.z * b.w;
            acc[3][0] += a.w * b.x; acc[3][1] += a.w * b.y; acc[3][2] += a.w * b.z; acc[3][3] += a.w * b.w;
        }
        __syncthreads();
    }
#pragma unroll
    for (int i = 0; i < 4; ++i)
        *(float4*)(C + (long)(bm + ty * 4 + i) * Nc + bn + tx * 4) =
            make_float4(acc[i][0], acc[i][1], acc[i][2], acc[i][3]);
}

extern "C" void kernel_launch(void* const* d_in, const int* in_sizes, int n_in,
                              void* d_out, int out_size, void* d_ws, size_t ws_size,
                              hipStream_t stream) {
    const float* t_all   = (const float*)d_in[0];
    const int*   t2e_all = (const int*)d_in[1];
    const int*   ei_all  = (const int*)d_in[2];
    const int*   es_all  = (const int*)d_in[3];
    const int*   ed_all  = (const int*)d_in[4];
    const float* Wgnn    = (const float*)d_in[5];
    const float* bgnn    = (const float*)d_in[6];
    const float* Wk      = (const float*)d_in[7];
    const float* bk      = (const float*)d_in[8];
    const float* Wq      = (const float*)d_in[9];
    const float* bq      = (const float*)d_in[10];
    const float* Wl      = (const float*)d_in[11];
    const float* bl      = (const float*)d_in[12];
    const float* ga      = (const float*)d_in[13];
    const float* gb      = (const float*)d_in[14];
    float* out = (float*)d_out;

    // workspace (~186 MB of 256 MiB)
    char* wsb = (char*)d_ws;
    size_t off = 0;
    unsigned short* zb    = (unsigned short*)(wsb + off); off += (size_t)BB * ME * DD * 2;  // 67.1 MB
    unsigned short* eeb   = (unsigned short*)(wsb + off); off += (size_t)BB * ME * DD * 2;  // 67.1 MB
    unsigned short* tb    = (unsigned short*)(wsb + off); off += (size_t)BB * NT * DD * 2;  // 16.8 MB
    unsigned short* nb    = (unsigned short*)(wsb + off); off += (size_t)BB * NT * DD * 2;  // 16.8 MB
    unsigned short* kmatb = (unsigned short*)(wsb + off); off += (size_t)BB * ME * DKK * 2; // 8.4 MB
    unsigned short* qmatb = (unsigned short*)(wsb + off); off += (size_t)BB * NT * DKK * 2; // 2.1 MB
    unsigned short* BtC   = (unsigned short*)(wsb + off); off += (size_t)576 * DD * 2;
    unsigned short* Wlt   = (unsigned short*)(wsb + off); off += (size_t)DD * DD * 2;
    unsigned short* Wqt   = (unsigned short*)(wsb + off); off += (size_t)DKK * DD * 2;
    float* Wgk   = (float*)(wsb + off); off += (size_t)DD * DKK * 4;
    float* biasC = (float*)(wsb + off); off += 576 * 4;
    float* dinv  = (float*)(wsb + off); off += (size_t)BB * ME * 4;
    float* wbuf  = (float*)(wsb + off); off += (size_t)BB * EA * 4;
    int* cntG  = (int*)(wsb + off); off += (size_t)BB * ME * 4;   // cntG+cntA contiguous
    int* cntA  = (int*)(wsb + off); off += (size_t)BB * NT * 4;
    int* offsG = (int*)(wsb + off); off += (size_t)BB * (ME + 1) * 4;
    int* curG  = (int*)(wsb + off); off += (size_t)BB * ME * 4;
    int2* csrG = (int2*)(wsb + off); off += (size_t)BB * EG * 8;
    int* offsA = (int*)(wsb + off); off += (size_t)BB * (NT + 1) * 4;
    int* curA  = (int*)(wsb + off); off += (size_t)BB * NT * 4;
    int2* csrA = (int2*)(wsb + off); off += (size_t)BB * EA * 8;

    // ---- one-time weight prep ----
    gemm_tiled<<<dim3(DD / 64, 1), 256, 0, stream>>>(Wgnn, Wk, Wgk, DD, DKK);  // Wgk = Wgnn@Wk
    k_wt<<<(DD * DD) / 256, 256, 0, stream>>>(Wl, Wlt);
    k_wt64<<<(DKK * DD) / 256, 256, 0, stream>>>(Wq, Wqt);
    k_wtC<<<(576 * DD) / 256, 256, 0, stream>>>(Wgnn, Wgk, BtC);
    k_biasC<<<1, 576, 0, stream>>>(bgnn, Wk, bk, biasC);

    // ---- batched CSR build (dinv computed in scan, fill is CSR-direct) ----
    hipMemsetAsync(cntG, 0, (size_t)BB * (ME + NT) * 4, stream);
    k_hist2<<<(BB * (EG + EA)) / 256, 256, 0, stream>>>(ei_all, ed_all, cntG, cntA);
    k_scan2<<<2 * BB, 1024, 0, stream>>>(cntG, offsG, curG, dinv, cntA, offsA, curA);
    k_fill2<<<(BB * (EG + EA)) / 256, 256, 0, stream>>>(
        ei_all, es_all, ed_all, t2e_all, dinv, curG, csrG, curA, csrA);

    // ---- bf16 tokens ----
    k_cast<<<(int)(((long)BB * NT * DD / 4) / 256), 256, 0, stream>>>(t_all, tb);

    // ---- GCN aggregate -> zb; fused (ee | k) = zb @ [Wgnn|Wgk] + [bgnn|bgk] ----
    k_gcn_gather<<<(BB * ME * 64) / 256, 256, 0, stream>>>(tb, t2e_all, dinv, offsG, csrG, zb);
    gemm_wide<9, 0><<<(BB * ME) / 64, 256, 0, stream>>>(
        zb, BtC, biasC, eeb, kmatb, nullptr, nullptr);

    // ---- q = tb @ Wq + bq ----
    gemm_bt_n64<<<(BB * NT) / 128, 256, 0, stream>>>(tb, Wqt, bq, qmatb);

    // ---- attention ----
    k_dots<<<(BB * EA) / 256, 256, 0, stream>>>(kmatb, qmatb, csrA, wbuf);
    k_att_gather<<<(BB * NT * 64) / 256, 256, 0, stream>>>(
        eeb, wbuf, offsA, csrA, t_all, ga, out, nb);

    // ---- final: out += tanh(gb) * (nb @ Wl + bl) ----
    gemm_wide<8, 1><<<(BB * NT) / 64, 256, 0, stream>>>(
        nb, Wlt, bl, nullptr, nullptr, out, gb);
}

// Round 8
// 439.202 us; speedup vs baseline: 5.0514x; 1.0433x over previous
//
#include <hip/hip_runtime.h>
#include <math.h>

// B=4, N=4096, M=16384, Eg=65536, Ea=65536, D=512, DK=64
#define BB 4
#define NT 4096
#define ME 16384
#define EG 65536
#define EA 65536
#define DD 512
#define DKK 64

using bf16x8 = __attribute__((ext_vector_type(8))) short;
using f32x4  = __attribute__((ext_vector_type(4))) float;

static __device__ __forceinline__ unsigned short f2bf(float f) {
    unsigned u = __float_as_uint(f);
    u += 0x7fffu + ((u >> 16) & 1u);
    return (unsigned short)(u >> 16);
}
static __device__ __forceinline__ void acc8(float* a, uint4 v, float s) {
    a[0] += s * __uint_as_float(v.x << 16);
    a[1] += s * __uint_as_float(v.x & 0xffff0000u);
    a[2] += s * __uint_as_float(v.y << 16);
    a[3] += s * __uint_as_float(v.y & 0xffff0000u);
    a[4] += s * __uint_as_float(v.z << 16);
    a[5] += s * __uint_as_float(v.z & 0xffff0000u);
    a[6] += s * __uint_as_float(v.w << 16);
    a[7] += s * __uint_as_float(v.w & 0xffff0000u);
}
static __device__ __forceinline__ uint4 pack8(const float* a) {
    uint4 o;
    o.x = (unsigned)f2bf(a[0]) | ((unsigned)f2bf(a[1]) << 16);
    o.y = (unsigned)f2bf(a[2]) | ((unsigned)f2bf(a[3]) << 16);
    o.z = (unsigned)f2bf(a[4]) | ((unsigned)f2bf(a[5]) << 16);
    o.w = (unsigned)f2bf(a[6]) | ((unsigned)f2bf(a[7]) << 16);
    return o;
}

// ---------------- batched CSR build ----------------
__global__ void k_hist2(const int* __restrict__ ei_all, const int* __restrict__ ed_all,
                        int* __restrict__ cntG, int* __restrict__ cntA) {
    int i = blockIdx.x * 256 + threadIdx.x;
    if (i < BB * EG) {
        int b = i >> 16, e = i & (EG - 1);
        int dst = ei_all[(size_t)b * 2 * EG + EG + e];
        atomicAdd(&cntG[b * ME + dst], 1);
    } else {
        int j = i - BB * EG;
        atomicAdd(&cntA[(j >> 16) * NT + ed_all[j]], 1);
    }
}

__global__ __launch_bounds__(1024) void k_scan2(
    const int* __restrict__ cntG, int* __restrict__ offsG, int* __restrict__ curG,
    float* __restrict__ dinv,
    const int* __restrict__ cntA, int* __restrict__ offsA, int* __restrict__ curA) {
    __shared__ int sums[1024];
    int tid = threadIdx.x;
    int bid = blockIdx.x;
    const int* cnt;
    int *offs, *cur;
    float* dv = nullptr;
    int C, nk;
    if (bid < BB) {
        cnt = cntG + bid * ME; offs = offsG + bid * (ME + 1); cur = curG + bid * ME;
        dv = dinv + bid * ME; C = ME / 1024; nk = ME;
    } else {
        int b = bid - BB;
        cnt = cntA + b * NT; offs = offsA + b * (NT + 1); cur = curA + b * NT;
        C = NT / 1024; nk = NT;
    }
    int local[16];
    int tot = 0;
    for (int i = 0; i < C; ++i) { local[i] = cnt[tid * C + i]; tot += local[i]; }
    sums[tid] = tot;
    __syncthreads();
    for (int d = 1; d < 1024; d <<= 1) {
        int v = (tid >= d) ? sums[tid - d] : 0;
        __syncthreads();
        sums[tid] += v;
        __syncthreads();
    }
    int run = sums[tid] - tot;
    for (int i = 0; i < C; ++i) {
        int idx = tid * C + i;
        offs[idx] = run;
        cur[idx] = run;
        if (dv) dv[idx] = rsqrtf((float)local[i] + 1.0f);  // +1 self loop
        run += local[i];
    }
    if (tid == 1023) offs[nk] = run;
}

// CSR-direct fill: graph slots hold (token_row, dinv-bits); attention slots hold (src, dst)
__global__ void k_fill2(const int* __restrict__ ei_all, const int* __restrict__ es_all,
                        const int* __restrict__ ed_all, const int* __restrict__ t2e_all,
                        const float* __restrict__ dinv,
                        int* __restrict__ curG, int2* __restrict__ csrG,
                        int* __restrict__ curA, int2* __restrict__ csrA) {
    int i = blockIdx.x * 256 + threadIdx.x;
    if (i < BB * EG) {
        int b = i >> 16, e = i & (EG - 1);
        const int* ei = ei_all + (size_t)b * 2 * EG;
        int s = ei[e], d = ei[EG + e];
        int p = atomicAdd(&curG[b * ME + d], 1);
        int2 v;
        v.x = t2e_all[(b << 14) + s];
        v.y = __float_as_int(dinv[b * ME + s]);
        csrG[(size_t)b * EG + p] = v;
    } else {
        int j = i - BB * EG;
        int b = j >> 16;
        int p = atomicAdd(&curA[b * NT + ed_all[j]], 1);
        int2 v;
        v.x = es_all[j];
        v.y = ed_all[j];
        csrA[(size_t)b * EA + p] = v;
    }
}

// ---------------- casts / weight prep ----------------
__global__ void k_cast(const float* __restrict__ x, unsigned short* __restrict__ xb) {
    long i = (long)blockIdx.x * blockDim.x + threadIdx.x;
    float4 v = *(const float4*)(x + (i << 2));
    ushort4 o;
    o.x = f2bf(v.x); o.y = f2bf(v.y); o.z = f2bf(v.z); o.w = f2bf(v.w);
    *(ushort4*)(xb + (i << 2)) = o;
}

__global__ void k_wt(const float* __restrict__ W, unsigned short* __restrict__ Wt) {
    int i = blockIdx.x * 256 + threadIdx.x;
    int n = i >> 9, k = i & 511;
    Wt[i] = f2bf(W[((long)k << 9) + n]);
}
__global__ void k_wt64(const float* __restrict__ W, unsigned short* __restrict__ Wt) {
    int i = blockIdx.x * 256 + threadIdx.x;
    int n = i >> 9, k = i & 511;
    Wt[i] = f2bf(W[k * 64 + n]);
}
// BtC[576][512]: rows 0..511 = Wgnn^T; rows 512..575 = Wgk^T
__global__ void k_wtC(const float* __restrict__ Wgnn, const float* __restrict__ Wgk,
                      unsigned short* __restrict__ BtC) {
    int i = blockIdx.x * 256 + threadIdx.x;
    int n = i >> 9, k = i & 511;
    BtC[i] = f2bf(n < 512 ? Wgnn[((long)k << 9) + n] : Wgk[k * 64 + (n - 512)]);
}
__global__ void k_biasC(const float* __restrict__ bgnn, const float* __restrict__ Wk,
                        const float* __restrict__ bk, float* __restrict__ biasC) {
    int tid = threadIdx.x;  // 576
    if (tid < 512) { biasC[tid] = bgnn[tid]; return; }
    int n = tid - 512;
    float s = bk[n];
    for (int k = 0; k < DD; ++k) s += bgnn[k] * Wk[k * 64 + n];
    biasC[tid] = s;
}

// ---------------- GCN aggregation: one wave per (b,m), 4-deep ILP ----------------
__global__ __launch_bounds__(256) void k_gcn_gather(
    const unsigned short* __restrict__ tb, const int* __restrict__ t2e_all,
    const float* __restrict__ dinv, const int* __restrict__ offsG,
    const int2* __restrict__ csrG, unsigned short* __restrict__ zb)
{
    int mg = (blockIdx.x * 256 + threadIdx.x) >> 6;   // [0, B*ME)
    int lane = threadIdx.x & 63;
    int b = mg >> 14;
    int m = mg & (ME - 1);
    const int* offs = offsG + b * (ME + 1);
    const int2* csr = csrG + (size_t)b * EG;
    const unsigned short* tl = tb + (((long)b * NT) << 9) + lane * 8;

    float dm = dinv[mg];
    uint4 vself = *(const uint4*)(tl + ((long)t2e_all[mg] << 9));
    float a[8] = {0, 0, 0, 0, 0, 0, 0, 0};
    int p = offs[m], end = offs[m + 1];
    for (; p + 4 <= end; p += 4) {
        int2 e0 = csr[p], e1 = csr[p + 1], e2 = csr[p + 2], e3 = csr[p + 3];
        uint4 r0 = *(const uint4*)(tl + ((long)e0.x << 9));
        uint4 r1 = *(const uint4*)(tl + ((long)e1.x << 9));
        uint4 r2 = *(const uint4*)(tl + ((long)e2.x << 9));
        uint4 r3 = *(const uint4*)(tl + ((long)e3.x << 9));
        acc8(a, r0, __int_as_float(e0.y));
        acc8(a, r1, __int_as_float(e1.y));
        acc8(a, r2, __int_as_float(e2.y));
        acc8(a, r3, __int_as_float(e3.y));
    }
    for (; p < end; ++p) {
        int2 e = csr[p];
        acc8(a, *(const uint4*)(tl + ((long)e.x << 9)), __int_as_float(e.y));
    }
    acc8(a, vself, dm);
#pragma unroll
    for (int j = 0; j < 8; ++j) a[j] *= dm;
    *(uint4*)(zb + ((long)mg << 9) + lane * 8) = pack8(a);
}

// ---------------- attention dots: one thread per CSR position ----------------
__global__ void k_dots(const unsigned short* __restrict__ kmatb,
                       const unsigned short* __restrict__ qmatb,
                       const int2* __restrict__ csrA, float* __restrict__ wbuf) {
    int p = blockIdx.x * 256 + threadIdx.x;   // [0, B*EA)
    int b = p >> 16;
    int2 sd = csrA[p];
    const uint4* kr = (const uint4*)(kmatb + ((long)(b * ME + sd.x) << 6));
    const uint4* qr = (const uint4*)(qmatb + ((long)(b * NT + sd.y) << 6));
    float dot = 0.0f;
#pragma unroll
    for (int j = 0; j < 8; ++j) {
        uint4 kv = kr[j];
        uint4 qv = qr[j];
        dot += __uint_as_float(kv.x << 16) * __uint_as_float(qv.x << 16)
             + __uint_as_float(kv.x & 0xffff0000u) * __uint_as_float(qv.x & 0xffff0000u)
             + __uint_as_float(kv.y << 16) * __uint_as_float(qv.y << 16)
             + __uint_as_float(kv.y & 0xffff0000u) * __uint_as_float(qv.y & 0xffff0000u)
             + __uint_as_float(kv.z << 16) * __uint_as_float(qv.z << 16)
             + __uint_as_float(kv.z & 0xffff0000u) * __uint_as_float(qv.z & 0xffff0000u)
             + __uint_as_float(kv.w << 16) * __uint_as_float(qv.w << 16)
             + __uint_as_float(kv.w & 0xffff0000u) * __uint_as_float(qv.w & 0xffff0000u);
    }
    wbuf[p] = expf(dot * 0.125f);  // /sqrt(64); softmax max-shift is exact no-op
}

// ---------------- attention aggregation: one wave per (b,n), 4-deep ILP ----------------
__global__ __launch_bounds__(256) void k_att_gather(
    const unsigned short* __restrict__ eeb, const float* __restrict__ wbuf,
    const int* __restrict__ offsA, const int2* __restrict__ csrA,
    const float* __restrict__ t_all, const float* __restrict__ ga,
    float* __restrict__ out, unsigned short* __restrict__ nb)
{
    int ng = (blockIdx.x * 256 + threadIdx.x) >> 6;   // [0, B*NT)
    int lane = threadIdx.x & 63;
    int b = ng >> 12;
    int n = ng & (NT - 1);
    const int* offs = offsA + b * (NT + 1);
    const int2* csr = csrA + (size_t)b * EA;
    const float* wb = wbuf + (size_t)b * EA;
    const unsigned short* el = eeb + (((size_t)b * ME) << 9) + lane * 8;

    float a[8] = {0, 0, 0, 0, 0, 0, 0, 0};
    float den = 0.0f;
    int p = offs[n], end = offs[n + 1];
    for (; p + 4 <= end; p += 4) {
        int s0 = csr[p].x, s1 = csr[p + 1].x, s2 = csr[p + 2].x, s3 = csr[p + 3].x;
        float w0 = wb[p], w1 = wb[p + 1], w2 = wb[p + 2], w3 = wb[p + 3];
        uint4 r0 = *(const uint4*)(el + ((long)s0 << 9));
        uint4 r1 = *(const uint4*)(el + ((long)s1 << 9));
        uint4 r2 = *(const uint4*)(el + ((long)s2 << 9));
        uint4 r3 = *(const uint4*)(el + ((long)s3 << 9));
        den += w0 + w1 + w2 + w3;
        acc8(a, r0, w0);
        acc8(a, r1, w1);
        acc8(a, r2, w2);
        acc8(a, r3, w3);
    }
    for (; p < end; ++p) {
        int s = csr[p].x;
        float w = wb[p];
        den += w;
        acc8(a, *(const uint4*)(el + ((long)s << 9)), w);
    }
    float g = tanhf(ga[0]);
    float inv = den > 0.0f ? g / den : 0.0f;
    const float* tr = t_all + ((long)ng << 9) + lane * 8;
    float4 t0 = *(const float4*)tr;
    float4 t1 = *(const float4*)(tr + 4);
    float o[8];
    o[0] = t0.x + inv * a[0]; o[1] = t0.y + inv * a[1];
    o[2] = t0.z + inv * a[2]; o[3] = t0.w + inv * a[3];
    o[4] = t1.x + inv * a[4]; o[5] = t1.y + inv * a[5];
    o[6] = t1.z + inv * a[6]; o[7] = t1.w + inv * a[7];
    float* op = out + ((long)ng << 9) + lane * 8;
    *(float4*)op = make_float4(o[0], o[1], o[2], o[3]);
    *(float4*)(op + 4) = make_float4(o[4], o[5], o[6], o[7]);
    *(uint4*)(nb + ((long)ng << 9) + lane * 8) = pack8(o);
}

// ---------------- bf16 MFMA GEMM: 128-row x (2*CB*16)-col block, XOR-swizzled LDS ----------------
// 256 threads = 4 waves (2 row x 2 col); wave tile = 64 rows x CB*16 cols.
// LDS slot s=(row*4+kc): holds global chunk kc ^ ((row>>1)&3)  (self-inverse; kills 8-way conflicts)
// MODE 0: cols<512 -> Cb bf16; cols>=512 -> Ck bf16 (fused k-proj).  MODE 1: Cf += tanh(gs[0])*(acc+bias)
template<int CB, int MODE>
__global__ __launch_bounds__(256, 2) void gemm_fused(
    const unsigned short* __restrict__ A,   // [M,512]
    const unsigned short* __restrict__ Bt,  // [gridDim.y*2*CB*16, 512]
    const float* __restrict__ bias,
    unsigned short* __restrict__ Cb, unsigned short* __restrict__ Ck,
    float* __restrict__ Cf, const float* __restrict__ gs)
{
    constexpr int BROWS = 2 * CB * 16;      // C-cols per block = B-rows staged
    __shared__ short As[128 * 32];          // 8 KB
    __shared__ short Bs[BROWS * 32];        // 18 KB (CB=9) / 16 KB (CB=8)
    int tid = threadIdx.x;
    int lane = tid & 63;
    int w = tid >> 6;
    int wm = w >> 1, wn = w & 1;
    long bm = (long)blockIdx.x * 128;
    int bcol = blockIdx.y * BROWS;
    const unsigned short* Bblk = Bt + (long)bcol * DD;

    f32x4 acc[4][CB] = {};

    for (int k0 = 0; k0 < DD; k0 += 32) {
        // stage A: slots tid, tid+256
#pragma unroll
        for (int i = 0; i < 2; ++i) {
            int s = tid + i * 256;
            int r = s >> 2;
            int gc = ((s & 3) ^ ((s >> 3) & 3)) * 8;
            __builtin_amdgcn_global_load_lds(
                (const __attribute__((address_space(1))) unsigned int*)(A + (bm + r) * DD + k0 + gc),
                (__attribute__((address_space(3))) unsigned int*)(As + s * 8), 16, 0, 0);
        }
        // stage B: CB/2 full rounds + 128-thread tail when CB odd (wave-uniform)
#pragma unroll
        for (int i = 0; i < CB / 2; ++i) {
            int s = tid + i * 256;
            int r = s >> 2;
            int gc = ((s & 3) ^ ((s >> 3) & 3)) * 8;
            __builtin_amdgcn_global_load_lds(
                (const __attribute__((address_space(1))) unsigned int*)(Bblk + (long)r * DD + k0 + gc),
                (__attribute__((address_space(3))) unsigned int*)(Bs + s * 8), 16, 0, 0);
        }
        if (CB & 1) {
            if (tid < 128) {
                int s = tid + (CB / 2) * 256;
                int r = s >> 2;
                int gc = ((s & 3) ^ ((s >> 3) & 3)) * 8;
                __builtin_amdgcn_global_load_lds(
                    (const __attribute__((address_space(1))) unsigned int*)(Bblk + (long)r * DD + k0 + gc),
                    (__attribute__((address_space(3))) unsigned int*)(Bs + s * 8), 16, 0, 0);
            }
        }
        __syncthreads();

        int cq = lane >> 4;
        bf16x8 af[4];
#pragma unroll
        for (int rb = 0; rb < 4; ++rb) {
            int r = wm * 64 + rb * 16 + (lane & 15);
            af[rb] = *(const bf16x8*)&As[(r * 4 + (cq ^ ((r >> 1) & 3))) * 8];
        }
#pragma unroll
        for (int cb = 0; cb < CB; ++cb) {
            int r = wn * (CB * 16) + cb * 16 + (lane & 15);
            bf16x8 bf = *(const bf16x8*)&Bs[(r * 4 + (cq ^ ((r >> 1) & 3))) * 8];
#pragma unroll
            for (int rb = 0; rb < 4; ++rb)
                acc[rb][cb] = __builtin_amdgcn_mfma_f32_16x16x32_bf16(af[rb], bf, acc[rb][cb], 0, 0, 0);
        }
        __syncthreads();
    }

    float g = (MODE == 1) ? tanhf(gs[0]) : 0.0f;
#pragma unroll
    for (int rb = 0; rb < 4; ++rb) {
        long row0 = bm + wm * 64 + rb * 16 + ((lane >> 4) << 2);
#pragma unroll
        for (int cb = 0; cb < CB; ++cb) {
            int col = bcol + wn * (CB * 16) + cb * 16 + (lane & 15);
            float bv = bias[col];
            if (MODE == 0) {
                if (col < 512) {
#pragma unroll
                    for (int r = 0; r < 4; ++r)
                        Cb[(row0 + r) * DD + col] = f2bf(acc[rb][cb][r] + bv);
                } else {
#pragma unroll
                    for (int r = 0; r < 4; ++r)
                        Ck[(row0 + r) * DKK + (col - 512)] = f2bf(acc[rb][cb][r] + bv);
                }
            } else {
#pragma unroll
                for (int r = 0; r < 4; ++r)
                    Cf[(row0 + r) * DD + col] += g * (acc[rb][cb][r] + bv);
            }
        }
    }
}

// ---------------- bf16 MFMA skinny GEMM (q-proj): Cb[M,64] = A[M,512]@Bt[64,512]^T + bias ----------------
__global__ __launch_bounds__(256) void gemm_bt_n64(
    const unsigned short* __restrict__ A, const unsigned short* __restrict__ Bt,
    const float* __restrict__ bias, unsigned short* __restrict__ Cb)
{
    __shared__ short As[128 * 32];
    __shared__ short Bs[64 * 32];
    int tid = threadIdx.x;
    int lane = tid & 63;
    int w = tid >> 6;
    int bm = blockIdx.x * 128;

    f32x4 acc[2][4] = {};

    int srow = tid >> 2;
    int scol = (tid & 3) * 8;
    const unsigned short* Ag0 = A + (long)(bm + srow) * DD + scol;
    const unsigned short* Ag1 = A + (long)(bm + 64 + srow) * DD + scol;
    const unsigned short* Bg = Bt + (long)srow * DD + scol;

    int ar = w * 32 + (lane & 15);
    int br = (lane & 15);
    int kq = (lane >> 4) * 8;

    for (int k0 = 0; k0 < DD; k0 += 32) {
        __builtin_amdgcn_global_load_lds(
            (const __attribute__((address_space(1))) unsigned int*)(Ag0 + k0),
            (__attribute__((address_space(3))) unsigned int*)(As + tid * 8), 16, 0, 0);
        __builtin_amdgcn_global_load_lds(
            (const __attribute__((address_space(1))) unsigned int*)(Ag1 + k0),
            (__attribute__((address_space(3))) unsigned int*)(As + 2048 + tid * 8), 16, 0, 0);
        __builtin_amdgcn_global_load_lds(
            (const __attribute__((address_space(1))) unsigned int*)(Bg + k0),
            (__attribute__((address_space(3))) unsigned int*)(Bs + tid * 8), 16, 0, 0);
        __syncthreads();

        bf16x8 af[2], bf[4];
#pragma unroll
        for (int rb = 0; rb < 2; ++rb)
            af[rb] = *(const bf16x8*)&As[(ar + rb * 16) * 32 + kq];
#pragma unroll
        for (int cb = 0; cb < 4; ++cb)
            bf[cb] = *(const bf16x8*)&Bs[(br + cb * 16) * 32 + kq];
#pragma unroll
        for (int rb = 0; rb < 2; ++rb)
#pragma unroll
            for (int cb = 0; cb < 4; ++cb)
                acc[rb][cb] = __builtin_amdgcn_mfma_f32_16x16x32_bf16(
                    af[rb], bf[cb], acc[rb][cb], 0, 0, 0);
        __syncthreads();
    }

#pragma unroll
    for (int rb = 0; rb < 2; ++rb) {
        int row0 = bm + w * 32 + rb * 16 + ((lane >> 4) << 2);
#pragma unroll
        for (int cb = 0; cb < 4; ++cb) {
            int col = cb * 16 + (lane & 15);
            float bv = bias[col];
#pragma unroll
            for (int r = 0; r < 4; ++r)
                Cb[(long)(row0 + r) * DKK + col] = f2bf(acc[rb][cb][r] + bv);
        }
    }
}

// ---------------- fp32 tiled GEMM (one-time Wgk = Wgnn @ Wk) ----------------
__global__ void gemm_tiled(const float* __restrict__ A, const float* __restrict__ Bw,
                           float* __restrict__ C, int K, int Nc) {
    __shared__ float As[16][64];
    __shared__ float Bs[16][64];
    int tid = threadIdx.x;
    int tx = tid & 15, ty = tid >> 4;
    int bm = blockIdx.x * 64, bn = blockIdx.y * 64;
    float acc[4][4] = {};
    int arow = bm + (tid >> 2);
    long aoff = (long)arow * K;
    int kk0 = (tid & 3) * 4;
    int arowl = tid >> 2;
    for (int k0 = 0; k0 < K; k0 += 16) {
        float4 av = *(const float4*)(A + aoff + k0 + kk0);
        As[kk0 + 0][arowl] = av.x;
        As[kk0 + 1][arowl] = av.y;
        As[kk0 + 2][arowl] = av.z;
        As[kk0 + 3][arowl] = av.w;
        float4 bv = *(const float4*)(Bw + (long)(k0 + (tid >> 4)) * Nc + bn + (tid & 15) * 4);
        *(float4*)&Bs[tid >> 4][(tid & 15) * 4] = bv;
        __syncthreads();
#pragma unroll
        for (int k = 0; k < 16; ++k) {
            float4 a = *(const float4*)&As[k][ty * 4];
            float4 b = *(const float4*)&Bs[k][tx * 4];
            acc[0][0] += a.x * b.x; acc[0][1] += a.x * b.y; acc[0][2] += a.x * b.z; acc[0][3] += a.x * b.w;
            acc[1][0] += a.y * b.x; acc[1][1] += a.y * b.y; acc[1][2] += a.y * b.z; acc[1][3] += a.y * b.w;
            acc[2][0] += a.z * b.x; acc[2][1] += a.z * b.y; acc[2][2] += a.z * b.z; acc[2][3] += a.z * b.w;
            acc[3][0] += a.w * b.x; acc[3][1] += a.w * b.y; acc[3][2] += a.w * b.z; acc[3][3] += a.w * b.w;
        }
        __syncthreads();
    }
#pragma unroll
    for (int i = 0; i < 4; ++i)
        *(float4*)(C + (long)(bm + ty * 4 + i) * Nc + bn + tx * 4) =
            make_float4(acc[i][0], acc[i][1], acc[i][2], acc[i][3]);
}

extern "C" void kernel_launch(void* const* d_in, const int* in_sizes, int n_in,
                              void* d_out, int out_size, void* d_ws, size_t ws_size,
                              hipStream_t stream) {
    const float* t_all   = (const float*)d_in[0];
    const int*   t2e_all = (const int*)d_in[1];
    const int*   ei_all  = (const int*)d_in[2];
    const int*   es_all  = (const int*)d_in[3];
    const int*   ed_all  = (const int*)d_in[4];
    const float* Wgnn    = (const float*)d_in[5];
    const float* bgnn    = (const float*)d_in[6];
    const float* Wk      = (const float*)d_in[7];
    const float* bk      = (const float*)d_in[8];
    const float* Wq      = (const float*)d_in[9];
    const float* bq      = (const float*)d_in[10];
    const float* Wl      = (const float*)d_in[11];
    const float* bl      = (const float*)d_in[12];
    const float* ga      = (const float*)d_in[13];
    const float* gb      = (const float*)d_in[14];
    float* out = (float*)d_out;

    // workspace (~186 MB of 256 MiB)
    char* wsb = (char*)d_ws;
    size_t off = 0;
    unsigned short* zb    = (unsigned short*)(wsb + off); off += (size_t)BB * ME * DD * 2;
    unsigned short* eeb   = (unsigned short*)(wsb + off); off += (size_t)BB * ME * DD * 2;
    unsigned short* tb    = (unsigned short*)(wsb + off); off += (size_t)BB * NT * DD * 2;
    unsigned short* nb    = (unsigned short*)(wsb + off); off += (size_t)BB * NT * DD * 2;
    unsigned short* kmatb = (unsigned short*)(wsb + off); off += (size_t)BB * ME * DKK * 2;
    unsigned short* qmatb = (unsigned short*)(wsb + off); off += (size_t)BB * NT * DKK * 2;
    unsigned short* BtC   = (unsigned short*)(wsb + off); off += (size_t)576 * DD * 2;
    unsigned short* Wlt   = (unsigned short*)(wsb + off); off += (size_t)DD * DD * 2;
    unsigned short* Wqt   = (unsigned short*)(wsb + off); off += (size_t)DKK * DD * 2;
    float* Wgk   = (float*)(wsb + off); off += (size_t)DD * DKK * 4;
    float* biasC = (float*)(wsb + off); off += 576 * 4;
    float* dinv  = (float*)(wsb + off); off += (size_t)BB * ME * 4;
    float* wbuf  = (float*)(wsb + off); off += (size_t)BB * EA * 4;
    int* cntG  = (int*)(wsb + off); off += (size_t)BB * ME * 4;   // cntG+cntA contiguous
    int* cntA  = (int*)(wsb + off); off += (size_t)BB * NT * 4;
    int* offsG = (int*)(wsb + off); off += (size_t)BB * (ME + 1) * 4;
    int* curG  = (int*)(wsb + off); off += (size_t)BB * ME * 4;
    int2* csrG = (int2*)(wsb + off); off += (size_t)BB * EG * 8;
    int* offsA = (int*)(wsb + off); off += (size_t)BB * (NT + 1) * 4;
    int* curA  = (int*)(wsb + off); off += (size_t)BB * NT * 4;
    int2* csrA = (int2*)(wsb + off); off += (size_t)BB * EA * 8;

    // ---- one-time weight prep ----
    gemm_tiled<<<dim3(DD / 64, 1), 256, 0, stream>>>(Wgnn, Wk, Wgk, DD, DKK);  // Wgk = Wgnn@Wk
    k_wt<<<(DD * DD) / 256, 256, 0, stream>>>(Wl, Wlt);
    k_wt64<<<(DKK * DD) / 256, 256, 0, stream>>>(Wq, Wqt);
    k_wtC<<<(576 * DD) / 256, 256, 0, stream>>>(Wgnn, Wgk, BtC);
    k_biasC<<<1, 576, 0, stream>>>(bgnn, Wk, bk, biasC);

    // ---- batched CSR build ----
    hipMemsetAsync(cntG, 0, (size_t)BB * (ME + NT) * 4, stream);
    k_hist2<<<(BB * (EG + EA)) / 256, 256, 0, stream>>>(ei_all, ed_all, cntG, cntA);
    k_scan2<<<2 * BB, 1024, 0, stream>>>(cntG, offsG, curG, dinv, cntA, offsA, curA);
    k_fill2<<<(BB * (EG + EA)) / 256, 256, 0, stream>>>(
        ei_all, es_all, ed_all, t2e_all, dinv, curG, csrG, curA, csrA);

    // ---- bf16 tokens ----
    k_cast<<<(int)(((long)BB * NT * DD / 4) / 256), 256, 0, stream>>>(t_all, tb);

    // ---- GCN aggregate -> zb; fused (ee | k) = zb @ [Wgnn|Wgk] + [bgnn|bgk] ----
    k_gcn_gather<<<(BB * ME * 64) / 256, 256, 0, stream>>>(tb, t2e_all, dinv, offsG, csrG, zb);
    gemm_fused<9, 0><<<dim3((BB * ME) / 128, 2), 256, 0, stream>>>(
        zb, BtC, biasC, eeb, kmatb, nullptr, nullptr);

    // ---- q = tb @ Wq + bq ----
    gemm_bt_n64<<<(BB * NT) / 128, 256, 0, stream>>>(tb, Wqt, bq, qmatb);

    // ---- attention ----
    k_dots<<<(BB * EA) / 256, 256, 0, stream>>>(kmatb, qmatb, csrA, wbuf);
    k_att_gather<<<(BB * NT * 64) / 256, 256, 0, stream>>>(
        eeb, wbuf, offsA, csrA, t_all, ga, out, nb);

    // ---- final: out += tanh(gb) * (nb @ Wl + bl) ----
    gemm_fused<8, 1><<<dim3((BB * NT) / 128, 2), 256, 0, stream>>>(
        nb, Wlt, bl, nullptr, nullptr, out, gb);
}

// Round 9
// 387.616 us; speedup vs baseline: 5.7237x; 1.1331x over previous
//
#include <hip/hip_runtime.h>
#include <math.h>

// B=4, N=4096, M=16384, Eg=65536, Ea=65536, D=512, DK=64
#define BB 4
#define NT 4096
#define ME 16384
#define EG 65536
#define EA 65536
#define DD 512
#define DKK 64

using bf16x8 = __attribute__((ext_vector_type(8))) short;
using f32x4  = __attribute__((ext_vector_type(4))) float;

static __device__ __forceinline__ unsigned short f2bf(float f) {
    unsigned u = __float_as_uint(f);
    u += 0x7fffu + ((u >> 16) & 1u);
    return (unsigned short)(u >> 16);
}
static __device__ __forceinline__ float bf2f(unsigned short u) {
    return __uint_as_float((unsigned)u << 16);
}
static __device__ __forceinline__ void acc8(float* a, uint4 v, float s) {
    a[0] += s * __uint_as_float(v.x << 16);
    a[1] += s * __uint_as_float(v.x & 0xffff0000u);
    a[2] += s * __uint_as_float(v.y << 16);
    a[3] += s * __uint_as_float(v.y & 0xffff0000u);
    a[4] += s * __uint_as_float(v.z << 16);
    a[5] += s * __uint_as_float(v.z & 0xffff0000u);
    a[6] += s * __uint_as_float(v.w << 16);
    a[7] += s * __uint_as_float(v.w & 0xffff0000u);
}
static __device__ __forceinline__ uint4 pack8(const float* a) {
    uint4 o;
    o.x = (unsigned)f2bf(a[0]) | ((unsigned)f2bf(a[1]) << 16);
    o.y = (unsigned)f2bf(a[2]) | ((unsigned)f2bf(a[3]) << 16);
    o.z = (unsigned)f2bf(a[4]) | ((unsigned)f2bf(a[5]) << 16);
    o.w = (unsigned)f2bf(a[6]) | ((unsigned)f2bf(a[7]) << 16);
    return o;
}

// ---------------- batched CSR build ----------------
__global__ void k_hist2(const int* __restrict__ ei_all, const int* __restrict__ ed_all,
                        int* __restrict__ cntG, int* __restrict__ cntA) {
    int i = blockIdx.x * 256 + threadIdx.x;
    if (i < BB * EG) {
        int b = i >> 16, e = i & (EG - 1);
        int dst = ei_all[(size_t)b * 2 * EG + EG + e];
        atomicAdd(&cntG[b * ME + dst], 1);
    } else {
        int j = i - BB * EG;
        atomicAdd(&cntA[(j >> 16) * NT + ed_all[j]], 1);
    }
}

__global__ __launch_bounds__(1024) void k_scan2(
    const int* __restrict__ cntG, int* __restrict__ offsG, int* __restrict__ curG,
    float* __restrict__ dinv,
    const int* __restrict__ cntA, int* __restrict__ offsA, int* __restrict__ curA) {
    __shared__ int sums[1024];
    int tid = threadIdx.x;
    int bid = blockIdx.x;
    const int* cnt;
    int *offs, *cur;
    float* dv = nullptr;
    int C, nk;
    if (bid < BB) {
        cnt = cntG + bid * ME; offs = offsG + bid * (ME + 1); cur = curG + bid * ME;
        dv = dinv + bid * ME; C = ME / 1024; nk = ME;
    } else {
        int b = bid - BB;
        cnt = cntA + b * NT; offs = offsA + b * (NT + 1); cur = curA + b * NT;
        C = NT / 1024; nk = NT;
    }
    int local[16];
    int tot = 0;
    for (int i = 0; i < C; ++i) { local[i] = cnt[tid * C + i]; tot += local[i]; }
    sums[tid] = tot;
    __syncthreads();
    for (int d = 1; d < 1024; d <<= 1) {
        int v = (tid >= d) ? sums[tid - d] : 0;
        __syncthreads();
        sums[tid] += v;
        __syncthreads();
    }
    int run = sums[tid] - tot;
    for (int i = 0; i < C; ++i) {
        int idx = tid * C + i;
        offs[idx] = run;
        cur[idx] = run;
        if (dv) dv[idx] = rsqrtf((float)local[i] + 1.0f);  // +1 self loop
        run += local[i];
    }
    if (tid == 1023) offs[nk] = run;
}

// CSR-direct fill: graph slots hold (token_row, dinv-bits); attention slots hold (src, dst)
__global__ void k_fill2(const int* __restrict__ ei_all, const int* __restrict__ es_all,
                        const int* __restrict__ ed_all, const int* __restrict__ t2e_all,
                        const float* __restrict__ dinv,
                        int* __restrict__ curG, int2* __restrict__ csrG,
                        int* __restrict__ curA, int2* __restrict__ csrA) {
    int i = blockIdx.x * 256 + threadIdx.x;
    if (i < BB * EG) {
        int b = i >> 16, e = i & (EG - 1);
        const int* ei = ei_all + (size_t)b * 2 * EG;
        int s = ei[e], d = ei[EG + e];
        int p = atomicAdd(&curG[b * ME + d], 1);
        int2 v;
        v.x = t2e_all[(b << 14) + s];
        v.y = __float_as_int(dinv[b * ME + s]);
        csrG[(size_t)b * EG + p] = v;
    } else {
        int j = i - BB * EG;
        int b = j >> 16;
        int p = atomicAdd(&curA[b * NT + ed_all[j]], 1);
        int2 v;
        v.x = es_all[j];
        v.y = ed_all[j];
        csrA[(size_t)b * EA + p] = v;
    }
}

// ---------------- casts / weight prep ----------------
__global__ void k_cast(const float* __restrict__ x, unsigned short* __restrict__ xb) {
    long i = (long)blockIdx.x * blockDim.x + threadIdx.x;
    float4 v = *(const float4*)(x + (i << 2));
    ushort4 o;
    o.x = f2bf(v.x); o.y = f2bf(v.y); o.z = f2bf(v.z); o.w = f2bf(v.w);
    *(ushort4*)(xb + (i << 2)) = o;
}

__global__ void k_wt(const float* __restrict__ W, unsigned short* __restrict__ Wt) {
    int i = blockIdx.x * 256 + threadIdx.x;
    int n = i >> 9, k = i & 511;
    Wt[i] = f2bf(W[((long)k << 9) + n]);
}
// BtT[640][512]: rows 0..511 = Wgnn^T; 512..575 = Wgk^T; 576..639 = Wq^T
__global__ void k_wtT(const float* __restrict__ Wgnn, const float* __restrict__ Wgk,
                      const float* __restrict__ Wq, unsigned short* __restrict__ BtT) {
    int i = blockIdx.x * 256 + threadIdx.x;  // 640*512
    int n = i >> 9, k = i & 511;
    float v;
    if (n < 512)      v = Wgnn[((long)k << 9) + n];
    else if (n < 576) v = Wgk[k * 64 + (n - 512)];
    else              v = Wq[k * 64 + (n - 576)];
    BtT[i] = f2bf(v);
}
// biasG[576] = [bgnn | bgk], bgk[n]=bk[n]+sum bgnn[k]Wk[k][n]; bias640 = [0..0 | bq]
__global__ void k_bias(const float* __restrict__ bgnn, const float* __restrict__ Wk,
                       const float* __restrict__ bk, const float* __restrict__ bq,
                       float* __restrict__ biasG, float* __restrict__ bias640) {
    int tid = threadIdx.x;  // 640
    if (tid < 512) { biasG[tid] = bgnn[tid]; bias640[tid] = 0.0f; return; }
    if (tid < 576) {
        int n = tid - 512;
        float s = bk[n];
        for (int k = 0; k < DD; ++k) s += bgnn[k] * Wk[k * 64 + n];
        biasG[tid] = s;
        bias640[tid] = 0.0f;
        return;
    }
    bias640[tid] = bq[tid - 576];
}

// ---------------- token GEMM: X[B*NT,640] = tb @ [Wgnn|Wgk|Wq]^T + bias640 ----------------
// 64-row x 320-col blocks (grid.y=2), 4 waves, wave = 64 rows x 80 cols; XOR-swizzled LDS.
// Output split: col<512 -> Xg bf16 [.,512]; col<576 -> Xk bf16 [.,64]; else -> qmatb bf16 [.,64]
__global__ __launch_bounds__(256, 2) void gemm_token(
    const unsigned short* __restrict__ A, const unsigned short* __restrict__ BtT,
    const float* __restrict__ bias640, unsigned short* __restrict__ Xg,
    unsigned short* __restrict__ Xk, unsigned short* __restrict__ qmatb)
{
    __shared__ short As[64 * 32];     // 4 KB
    __shared__ short Bs[320 * 32];    // 20 KB
    int tid = threadIdx.x;
    int lane = tid & 63;
    int w = tid >> 6;
    long bm = (long)blockIdx.x * 64;
    int bcol = blockIdx.y * 320;
    const unsigned short* Bblk = BtT + (long)bcol * DD;

    f32x4 acc[4][5] = {};

    for (int k0 = 0; k0 < DD; k0 += 32) {
        {
            int s = tid;
            int r = s >> 2;
            int gc = ((s & 3) ^ ((s >> 3) & 3)) * 8;
            __builtin_amdgcn_global_load_lds(
                (const __attribute__((address_space(1))) unsigned int*)(A + (bm + r) * DD + k0 + gc),
                (__attribute__((address_space(3))) unsigned int*)(As + s * 8), 16, 0, 0);
        }
#pragma unroll
        for (int i = 0; i < 5; ++i) {
            int s = tid + i * 256;
            int r = s >> 2;
            int gc = ((s & 3) ^ ((s >> 3) & 3)) * 8;
            __builtin_amdgcn_global_load_lds(
                (const __attribute__((address_space(1))) unsigned int*)(Bblk + (long)r * DD + k0 + gc),
                (__attribute__((address_space(3))) unsigned int*)(Bs + s * 8), 16, 0, 0);
        }
        __syncthreads();

        int cq = lane >> 4;
        bf16x8 af[4];
#pragma unroll
        for (int rb = 0; rb < 4; ++rb) {
            int r = rb * 16 + (lane & 15);
            af[rb] = *(const bf16x8*)&As[(r * 4 + (cq ^ ((r >> 1) & 3))) * 8];
        }
#pragma unroll
        for (int cb = 0; cb < 5; ++cb) {
            int r = w * 80 + cb * 16 + (lane & 15);
            bf16x8 bf = *(const bf16x8*)&Bs[(r * 4 + (cq ^ ((r >> 1) & 3))) * 8];
#pragma unroll
            for (int rb = 0; rb < 4; ++rb)
                acc[rb][cb] = __builtin_amdgcn_mfma_f32_16x16x32_bf16(af[rb], bf, acc[rb][cb], 0, 0, 0);
        }
        __syncthreads();
    }

#pragma unroll
    for (int rb = 0; rb < 4; ++rb) {
        long row0 = bm + rb * 16 + ((lane >> 4) << 2);
#pragma unroll
        for (int cb = 0; cb < 5; ++cb) {
            int col = bcol + w * 80 + cb * 16 + (lane & 15);
            float bv = bias640[col];
            if (col < 512) {
#pragma unroll
                for (int r = 0; r < 4; ++r)
                    Xg[(row0 + r) * DD + col] = f2bf(acc[rb][cb][r] + bv);
            } else if (col < 576) {
#pragma unroll
                for (int r = 0; r < 4; ++r)
                    Xk[(row0 + r) * DKK + (col - 512)] = f2bf(acc[rb][cb][r] + bv);
            } else {
#pragma unroll
                for (int r = 0; r < 4; ++r)
                    qmatb[(row0 + r) * DKK + (col - 576)] = f2bf(acc[rb][cb][r] + bv);
            }
        }
    }
}

// ---------------- GCN aggregation in projected space: one wave per (b,m) ----------------
// eeb[m,c] = bf16( dm*(dm*Xg[self,c] + sum ds*Xg[src,c]) + bgnn[c] )
// kmatb[m,l] = bf16( dm*(dm*Xk[self,l] + sum ds*Xk[src,l]) + bgk[l] )
__global__ __launch_bounds__(256) void k_gcn_gather(
    const unsigned short* __restrict__ Xg, const unsigned short* __restrict__ Xk,
    const int* __restrict__ t2e_all, const float* __restrict__ dinv,
    const int* __restrict__ offsG, const int2* __restrict__ csrG,
    const float* __restrict__ biasG,
    unsigned short* __restrict__ eeb, unsigned short* __restrict__ kmatb)
{
    int mg = (blockIdx.x * 256 + threadIdx.x) >> 6;   // [0, B*ME)
    int lane = threadIdx.x & 63;
    int b = mg >> 14;
    int m = mg & (ME - 1);
    const int* offs = offsG + b * (ME + 1);
    const int2* csr = csrG + (size_t)b * EG;
    const unsigned short* gl = Xg + (((long)b * NT) << 9) + lane * 8;
    const unsigned short* kl = Xk + ((long)b * NT) * DKK + lane;

    float dm = dinv[mg];
    int self = t2e_all[mg];
    uint4 vself = *(const uint4*)(gl + ((long)self << 9));
    float kself = bf2f(kl[(long)self * DKK]);

    float a[8] = {0, 0, 0, 0, 0, 0, 0, 0};
    float ak = 0.0f;
    int p = offs[m], end = offs[m + 1];
    for (; p + 4 <= end; p += 4) {
        int2 e0 = csr[p], e1 = csr[p + 1], e2 = csr[p + 2], e3 = csr[p + 3];
        uint4 r0 = *(const uint4*)(gl + ((long)e0.x << 9));
        uint4 r1 = *(const uint4*)(gl + ((long)e1.x << 9));
        uint4 r2 = *(const uint4*)(gl + ((long)e2.x << 9));
        uint4 r3 = *(const uint4*)(gl + ((long)e3.x << 9));
        float k0 = bf2f(kl[(long)e0.x * DKK]);
        float k1 = bf2f(kl[(long)e1.x * DKK]);
        float k2 = bf2f(kl[(long)e2.x * DKK]);
        float k3 = bf2f(kl[(long)e3.x * DKK]);
        float w0 = __int_as_float(e0.y), w1 = __int_as_float(e1.y);
        float w2 = __int_as_float(e2.y), w3 = __int_as_float(e3.y);
        acc8(a, r0, w0); ak += w0 * k0;
        acc8(a, r1, w1); ak += w1 * k1;
        acc8(a, r2, w2); ak += w2 * k2;
        acc8(a, r3, w3); ak += w3 * k3;
    }
    for (; p < end; ++p) {
        int2 e = csr[p];
        float w = __int_as_float(e.y);
        acc8(a, *(const uint4*)(gl + ((long)e.x << 9)), w);
        ak += w * bf2f(kl[(long)e.x * DKK]);
    }
    acc8(a, vself, dm);
    ak += dm * kself;

    const float* bg = biasG + lane * 8;
    float4 b0 = *(const float4*)bg;
    float4 b1 = *(const float4*)(bg + 4);
    a[0] = dm * a[0] + b0.x; a[1] = dm * a[1] + b0.y;
    a[2] = dm * a[2] + b0.z; a[3] = dm * a[3] + b0.w;
    a[4] = dm * a[4] + b1.x; a[5] = dm * a[5] + b1.y;
    a[6] = dm * a[6] + b1.z; a[7] = dm * a[7] + b1.w;
    *(uint4*)(eeb + ((long)mg << 9) + lane * 8) = pack8(a);
    kmatb[(long)mg * DKK + lane] = f2bf(dm * ak + biasG[512 + lane]);
}

// ---------------- attention dots: one thread per CSR position ----------------
__global__ void k_dots(const unsigned short* __restrict__ kmatb,
                       const unsigned short* __restrict__ qmatb,
                       const int2* __restrict__ csrA, float* __restrict__ wbuf) {
    int p = blockIdx.x * 256 + threadIdx.x;   // [0, B*EA)
    int b = p >> 16;
    int2 sd = csrA[p];
    const uint4* kr = (const uint4*)(kmatb + ((long)(b * ME + sd.x) << 6));
    const uint4* qr = (const uint4*)(qmatb + ((long)(b * NT + sd.y) << 6));
    float dot = 0.0f;
#pragma unroll
    for (int j = 0; j < 8; ++j) {
        uint4 kv = kr[j];
        uint4 qv = qr[j];
        dot += __uint_as_float(kv.x << 16) * __uint_as_float(qv.x << 16)
             + __uint_as_float(kv.x & 0xffff0000u) * __uint_as_float(qv.x & 0xffff0000u)
             + __uint_as_float(kv.y << 16) * __uint_as_float(qv.y << 16)
             + __uint_as_float(kv.y & 0xffff0000u) * __uint_as_float(qv.y & 0xffff0000u)
             + __uint_as_float(kv.z << 16) * __uint_as_float(qv.z << 16)
             + __uint_as_float(kv.z & 0xffff0000u) * __uint_as_float(qv.z & 0xffff0000u)
             + __uint_as_float(kv.w << 16) * __uint_as_float(qv.w << 16)
             + __uint_as_float(kv.w & 0xffff0000u) * __uint_as_float(qv.w & 0xffff0000u);
    }
    wbuf[p] = expf(dot * 0.125f);  // /sqrt(64); softmax max-shift is exact no-op
}

// ---------------- attention aggregation: one wave per (b,n), 4-deep ILP ----------------
__global__ __launch_bounds__(256) void k_att_gather(
    const unsigned short* __restrict__ eeb, const float* __restrict__ wbuf,
    const int* __restrict__ offsA, const int2* __restrict__ csrA,
    const float* __restrict__ t_all, const float* __restrict__ ga,
    float* __restrict__ out, unsigned short* __restrict__ nb)
{
    int ng = (blockIdx.x * 256 + threadIdx.x) >> 6;   // [0, B*NT)
    int lane = threadIdx.x & 63;
    int b = ng >> 12;
    int n = ng & (NT - 1);
    const int* offs = offsA + b * (NT + 1);
    const int2* csr = csrA + (size_t)b * EA;
    const float* wb = wbuf + (size_t)b * EA;
    const unsigned short* el = eeb + (((size_t)b * ME) << 9) + lane * 8;

    float a[8] = {0, 0, 0, 0, 0, 0, 0, 0};
    float den = 0.0f;
    int p = offs[n], end = offs[n + 1];
    for (; p + 4 <= end; p += 4) {
        int s0 = csr[p].x, s1 = csr[p + 1].x, s2 = csr[p + 2].x, s3 = csr[p + 3].x;
        float w0 = wb[p], w1 = wb[p + 1], w2 = wb[p + 2], w3 = wb[p + 3];
        uint4 r0 = *(const uint4*)(el + ((long)s0 << 9));
        uint4 r1 = *(const uint4*)(el + ((long)s1 << 9));
        uint4 r2 = *(const uint4*)(el + ((long)s2 << 9));
        uint4 r3 = *(const uint4*)(el + ((long)s3 << 9));
        den += w0 + w1 + w2 + w3;
        acc8(a, r0, w0);
        acc8(a, r1, w1);
        acc8(a, r2, w2);
        acc8(a, r3, w3);
    }
    for (; p < end; ++p) {
        int s = csr[p].x;
        float w = wb[p];
        den += w;
        acc8(a, *(const uint4*)(el + ((long)s << 9)), w);
    }
    float g = tanhf(ga[0]);
    float inv = den > 0.0f ? g / den : 0.0f;
    const float* tr = t_all + ((long)ng << 9) + lane * 8;
    float4 t0 = *(const float4*)tr;
    float4 t1 = *(const float4*)(tr + 4);
    float o[8];
    o[0] = t0.x + inv * a[0]; o[1] = t0.y + inv * a[1];
    o[2] = t0.z + inv * a[2]; o[3] = t0.w + inv * a[3];
    o[4] = t1.x + inv * a[4]; o[5] = t1.y + inv * a[5];
    o[6] = t1.z + inv * a[6]; o[7] = t1.w + inv * a[7];
    float* op = out + ((long)ng << 9) + lane * 8;
    *(float4*)op = make_float4(o[0], o[1], o[2], o[3]);
    *(float4*)(op + 4) = make_float4(o[4], o[5], o[6], o[7]);
    *(uint4*)(nb + ((long)ng << 9) + lane * 8) = pack8(o);
}

// ---------------- final linear: 128-row x 256-col blocks, XOR-swizzled LDS ----------------
// Cf += tanh(gs[0]) * (A @ Bt^T + bias)
__global__ __launch_bounds__(256, 2) void gemm_final(
    const unsigned short* __restrict__ A, const unsigned short* __restrict__ Bt,
    const float* __restrict__ bias, float* __restrict__ Cf, const float* __restrict__ gs)
{
    constexpr int CB = 8;
    constexpr int BROWS = 2 * CB * 16;      // 256
    __shared__ short As[128 * 32];
    __shared__ short Bs[BROWS * 32];
    int tid = threadIdx.x;
    int lane = tid & 63;
    int w = tid >> 6;
    int wm = w >> 1, wn = w & 1;
    long bm = (long)blockIdx.x * 128;
    int bcol = blockIdx.y * BROWS;
    const unsigned short* Bblk = Bt + (long)bcol * DD;

    f32x4 acc[4][CB] = {};

    for (int k0 = 0; k0 < DD; k0 += 32) {
#pragma unroll
        for (int i = 0; i < 2; ++i) {
            int s = tid + i * 256;
            int r = s >> 2;
            int gc = ((s & 3) ^ ((s >> 3) & 3)) * 8;
            __builtin_amdgcn_global_load_lds(
                (const __attribute__((address_space(1))) unsigned int*)(A + (bm + r) * DD + k0 + gc),
                (__attribute__((address_space(3))) unsigned int*)(As + s * 8), 16, 0, 0);
        }
#pragma unroll
        for (int i = 0; i < CB / 2; ++i) {
            int s = tid + i * 256;
            int r = s >> 2;
            int gc = ((s & 3) ^ ((s >> 3) & 3)) * 8;
            __builtin_amdgcn_global_load_lds(
                (const __attribute__((address_space(1))) unsigned int*)(Bblk + (long)r * DD + k0 + gc),
                (__attribute__((address_space(3))) unsigned int*)(Bs + s * 8), 16, 0, 0);
        }
        __syncthreads();

        int cq = lane >> 4;
        bf16x8 af[4];
#pragma unroll
        for (int rb = 0; rb < 4; ++rb) {
            int r = wm * 64 + rb * 16 + (lane & 15);
            af[rb] = *(const bf16x8*)&As[(r * 4 + (cq ^ ((r >> 1) & 3))) * 8];
        }
#pragma unroll
        for (int cb = 0; cb < CB; ++cb) {
            int r = wn * (CB * 16) + cb * 16 + (lane & 15);
            bf16x8 bf = *(const bf16x8*)&Bs[(r * 4 + (cq ^ ((r >> 1) & 3))) * 8];
#pragma unroll
            for (int rb = 0; rb < 4; ++rb)
                acc[rb][cb] = __builtin_amdgcn_mfma_f32_16x16x32_bf16(af[rb], bf, acc[rb][cb], 0, 0, 0);
        }
        __syncthreads();
    }

    float g = tanhf(gs[0]);
#pragma unroll
    for (int rb = 0; rb < 4; ++rb) {
        long row0 = bm + wm * 64 + rb * 16 + ((lane >> 4) << 2);
#pragma unroll
        for (int cb = 0; cb < CB; ++cb) {
            int col = bcol + wn * (CB * 16) + cb * 16 + (lane & 15);
            float bv = bias[col];
#pragma unroll
            for (int r = 0; r < 4; ++r)
                Cf[(row0 + r) * DD + col] += g * (acc[rb][cb][r] + bv);
        }
    }
}

// ---------------- fp32 tiled GEMM (one-time Wgk = Wgnn @ Wk) ----------------
__global__ void gemm_tiled(const float* __restrict__ A, const float* __restrict__ Bw,
                           float* __restrict__ C, int K, int Nc) {
    __shared__ float As[16][64];
    __shared__ float Bs[16][64];
    int tid = threadIdx.x;
    int tx = tid & 15, ty = tid >> 4;
    int bm = blockIdx.x * 64, bn = blockIdx.y * 64;
    float acc[4][4] = {};
    int arow = bm + (tid >> 2);
    long aoff = (long)arow * K;
    int kk0 = (tid & 3) * 4;
    int arowl = tid >> 2;
    for (int k0 = 0; k0 < K; k0 += 16) {
        float4 av = *(const float4*)(A + aoff + k0 + kk0);
        As[kk0 + 0][arowl] = av.x;
        As[kk0 + 1][arowl] = av.y;
        As[kk0 + 2][arowl] = av.z;
        As[kk0 + 3][arowl] = av.w;
        float4 bv = *(const float4*)(Bw + (long)(k0 + (tid >> 4)) * Nc + bn + (tid & 15) * 4);
        *(float4*)&Bs[tid >> 4][(tid & 15) * 4] = bv;
        __syncthreads();
#pragma unroll
        for (int k = 0; k < 16; ++k) {
            float4 a = *(const float4*)&As[k][ty * 4];
            float4 b = *(const float4*)&Bs[k][tx * 4];
            acc[0][0] += a.x * b.x; acc[0][1] += a.x * b.y; acc[0][2] += a.x * b.z; acc[0][3] += a.x * b.w;
            acc[1][0] += a.y * b.x; acc[1][1] += a.y * b.y; acc[1][2] += a.y * b.z; acc[1][3] += a.y * b.w;
            acc[2][0] += a.z * b.x; acc[2][1] += a.z * b.y; acc[2][2] += a.z * b.z; acc[2][3] += a.z * b.w;
            acc[3][0] += a.w * b.x; acc[3][1] += a.w * b.y; acc[3][2] += a.w * b.z; acc[3][3] += a.w * b.w;
        }
        __syncthreads();
    }
#pragma unroll
    for (int i = 0; i < 4; ++i)
        *(float4*)(C + (long)(bm + ty * 4 + i) * Nc + bn + tx * 4) =
            make_float4(acc[i][0], acc[i][1], acc[i][2], acc[i][3]);
}

extern "C" void kernel_launch(void* const* d_in, const int* in_sizes, int n_in,
                              void* d_out, int out_size, void* d_ws, size_t ws_size,
                              hipStream_t stream) {
    const float* t_all   = (const float*)d_in[0];
    const int*   t2e_all = (const int*)d_in[1];
    const int*   ei_all  = (const int*)d_in[2];
    const int*   es_all  = (const int*)d_in[3];
    const int*   ed_all  = (const int*)d_in[4];
    const float* Wgnn    = (const float*)d_in[5];
    const float* bgnn    = (const float*)d_in[6];
    const float* Wk      = (const float*)d_in[7];
    const float* bk      = (const float*)d_in[8];
    const float* Wq      = (const float*)d_in[9];
    const float* bq      = (const float*)d_in[10];
    const float* Wl      = (const float*)d_in[11];
    const float* bl      = (const float*)d_in[12];
    const float* ga      = (const float*)d_in[13];
    const float* gb      = (const float*)d_in[14];
    float* out = (float*)d_out;

    // workspace (~140 MB of 256 MiB)
    char* wsb = (char*)d_ws;
    size_t off = 0;
    unsigned short* eeb   = (unsigned short*)(wsb + off); off += (size_t)BB * ME * DD * 2;  // 67.1 MB
    unsigned short* tb    = (unsigned short*)(wsb + off); off += (size_t)BB * NT * DD * 2;  // 16.8 MB
    unsigned short* Xg    = (unsigned short*)(wsb + off); off += (size_t)BB * NT * DD * 2;  // 16.8 MB
    unsigned short* nb    = (unsigned short*)(wsb + off); off += (size_t)BB * NT * DD * 2;  // 16.8 MB
    unsigned short* Xk    = (unsigned short*)(wsb + off); off += (size_t)BB * NT * DKK * 2; // 2.1 MB
    unsigned short* qmatb = (unsigned short*)(wsb + off); off += (size_t)BB * NT * DKK * 2; // 2.1 MB
    unsigned short* kmatb = (unsigned short*)(wsb + off); off += (size_t)BB * ME * DKK * 2; // 8.4 MB
    unsigned short* BtT   = (unsigned short*)(wsb + off); off += (size_t)640 * DD * 2;
    unsigned short* Wlt   = (unsigned short*)(wsb + off); off += (size_t)DD * DD * 2;
    float* Wgk     = (float*)(wsb + off); off += (size_t)DD * DKK * 4;
    float* biasG   = (float*)(wsb + off); off += 576 * 4;
    float* bias640 = (float*)(wsb + off); off += 640 * 4;
    float* dinv  = (float*)(wsb + off); off += (size_t)BB * ME * 4;
    float* wbuf  = (float*)(wsb + off); off += (size_t)BB * EA * 4;
    int* cntG  = (int*)(wsb + off); off += (size_t)BB * ME * 4;   // cntG+cntA contiguous
    int* cntA  = (int*)(wsb + off); off += (size_t)BB * NT * 4;
    int* offsG = (int*)(wsb + off); off += (size_t)BB * (ME + 1) * 4;
    int* curG  = (int*)(wsb + off); off += (size_t)BB * ME * 4;
    int2* csrG = (int2*)(wsb + off); off += (size_t)BB * EG * 8;
    int* offsA = (int*)(wsb + off); off += (size_t)BB * (NT + 1) * 4;
    int* curA  = (int*)(wsb + off); off += (size_t)BB * NT * 4;
    int2* csrA = (int2*)(wsb + off); off += (size_t)BB * EA * 8;

    // ---- one-time weight prep ----
    gemm_tiled<<<dim3(DD / 64, 1), 256, 0, stream>>>(Wgnn, Wk, Wgk, DD, DKK);  // Wgk = Wgnn@Wk
    k_wt<<<(DD * DD) / 256, 256, 0, stream>>>(Wl, Wlt);
    k_wtT<<<(640 * DD) / 256, 256, 0, stream>>>(Wgnn, Wgk, Wq, BtT);
    k_bias<<<1, 640, 0, stream>>>(bgnn, Wk, bk, bq, biasG, bias640);

    // ---- batched CSR build ----
    hipMemsetAsync(cntG, 0, (size_t)BB * (ME + NT) * 4, stream);
    k_hist2<<<(BB * (EG + EA)) / 256, 256, 0, stream>>>(ei_all, ed_all, cntG, cntA);
    k_scan2<<<2 * BB, 1024, 0, stream>>>(cntG, offsG, curG, dinv, cntA, offsA, curA);
    k_fill2<<<(BB * (EG + EA)) / 256, 256, 0, stream>>>(
        ei_all, es_all, ed_all, t2e_all, dinv, curG, csrG, curA, csrA);

    // ---- bf16 tokens, then token projection X = tb @ [Wgnn|Wgk|Wq] (+bq on q cols) ----
    k_cast<<<(int)(((long)BB * NT * DD / 4) / 256), 256, 0, stream>>>(t_all, tb);
    gemm_token<<<dim3((BB * NT) / 64, 2), 256, 0, stream>>>(tb, BtT, bias640, Xg, Xk, qmatb);

    // ---- GCN aggregation in projected space -> eeb, kmatb directly ----
    k_gcn_gather<<<(BB * ME * 64) / 256, 256, 0, stream>>>(
        Xg, Xk, t2e_all, dinv, offsG, csrG, biasG, eeb, kmatb);

    // ---- attention ----
    k_dots<<<(BB * EA) / 256, 256, 0, stream>>>(kmatb, qmatb, csrA, wbuf);
    k_att_gather<<<(BB * NT * 64) / 256, 256, 0, stream>>>(
        eeb, wbuf, offsA, csrA, t_all, ga, out, nb);

    // ---- final: out += tanh(gb) * (nb @ Wl + bl) ----
    gemm_final<<<dim3((BB * NT) / 128, 2), 256, 0, stream>>>(nb, Wlt, bl, out, gb);
}